// Round 5
// baseline (599.456 us; speedup 1.0000x reference)
//
#include <hip/hip_runtime.h>
#include <hip/hip_bf16.h>
#include <hip/hip_cooperative_groups.h>
#include <cstdint>

// LSTMCell B=4096, IN=H=2048. Fast path: ONE cooperative kernel:
//   phase 0: convert fp32->bf16 concat layout (W panel converted by its 8
//            consumer blocks -> XCD-L2-local), grid.sync()
//   phase 1: persistent fused GEMM (2 tiles/block, 8-phase schedule, T2
//            swizzle + counted vmcnt + setprio) + LSTM pointwise epilogue,
//            C prefetched to registers, no inter-tile drain (P8's vmcnt(4)
//            already covers the handoff slots).
// Coop-launch failure falls back to split convert + non-coop GEMM.
// Small-ws fallback: probe + ds_write GEMM + separate pointwise.

namespace cg = cooperative_groups;

#define B_DIM 4096
#define K_DIM 2048            // IN == H
#define NG    8192            // 4*H
#define BHT   (B_DIM * K_DIM) // B*H elements per output tensor

// ws element-layout (bf16 elements) for the fast path:
//   A [4096][4096] = [X | H] rows, at 0                  (16M els, 32 MB)
//   W [8192][4096] = [Wx_g | Wh_g] row g*2048+j, at 16M  (32M els, 64 MB)
#define CONV_W_ELS  (16u << 20)
#define CONV_TOTAL  (48u << 20)             // 48M els = 96 MB
#define FAST_NEED   ((size_t)CONV_TOTAL * 2 + 65536)  // 96 MB + pad (overstage reads)

#define NTILE 64              // K tiles: 4096 / 64
#define ASHIFT ((ptrdiff_t)8 * 256 * 8192)  // A base delta bm -> bm+8 (16 MB)

using bf16x8_t  = __attribute__((ext_vector_type(8))) __bf16;
using floatx4_t = __attribute__((ext_vector_type(4))) float;
using ushort8_t = __attribute__((ext_vector_type(8))) unsigned short;

__device__ __forceinline__ float bf_bits2f(unsigned short u) {
    return __builtin_bit_cast(float, ((unsigned int)u) << 16);
}
__device__ __forceinline__ unsigned short f2bf_bits(float f) {
    return __builtin_bit_cast(unsigned short, __float2bfloat16(f));
}
__device__ __forceinline__ float sigmoid_f(float x) {
    return 1.0f / (1.0f + __expf(-x));
}
__device__ __forceinline__ float tanh_f(float x) {
    float ax = fabsf(x);
    float e  = __expf(-2.0f * ax);
    float t  = (1.0f - e) / (1.0f + e);
    return copysignf(t, x);
}

struct SrcPtrs { const void* p[10]; };  // X,H,Wx0..3,Wh0..3

// Per-wave dtype detect from raw X words.
__device__ __forceinline__ int detect_f32(const unsigned int* X, int lane) {
    const unsigned int w = X[lane];
    const unsigned short hi = (unsigned short)(w >> 16);
    const unsigned short lo = (unsigned short)(w & 0xFFFFu);
    auto sane = [](unsigned short h) -> int {
        const int e = (h >> 7) & 0xFF;
        return (e >= 90 && e <= 140) || ((h & 0x7FFF) == 0);
    };
    const unsigned long long bh = __ballot(sane(hi));
    const unsigned long long bl = __ballot(sane(lo));
    const int cnt = __popcll(bh) + __popcll(bl);  // bf16 ~128, fp32 ~77
    return (cnt >= 112) ? 0 : 1;
}

__device__ __forceinline__ ushort8_t cvt_or_copy8(const void* src, size_t soff, int isF32) {
    if (isF32) {
        const float* s = (const float*)src + soff;
        const float4 f0 = *reinterpret_cast<const float4*>(s);
        const float4 f1 = *reinterpret_cast<const float4*>(s + 4);
        return (ushort8_t){f2bf_bits(f0.x), f2bf_bits(f0.y), f2bf_bits(f0.z), f2bf_bits(f0.w),
                           f2bf_bits(f1.x), f2bf_bits(f1.y), f2bf_bits(f1.z), f2bf_bits(f1.w)};
    }
    return *reinterpret_cast<const ushort8_t*>((const unsigned short*)src + soff);
}

// ---------------------------------------------------------------------------
// Dtype probe (fallback paths only).
// ---------------------------------------------------------------------------
__global__ void dtype_probe_kernel(const unsigned int* __restrict__ X,
                                   int* __restrict__ flag) {
    const int f = detect_f32(X, threadIdx.x & 63);
    if (threadIdx.x == 0) *flag = f;
}

// ---------------------------------------------------------------------------
// Standalone convert (non-coop fallback): build concat layout; grid-stride.
// ---------------------------------------------------------------------------
__global__ __launch_bounds__(256) void convert_kernel(
    SrcPtrs srcs, unsigned short* __restrict__ dst)
{
    const int isF32 = detect_f32((const unsigned int*)srcs.p[0], threadIdx.x & 63);

    for (unsigned int v = blockIdx.x; v < (CONV_TOTAL / 2048); v += gridDim.x) {
        const unsigned int idx8 = (v * 256u + threadIdx.x) * 8u;
        const unsigned int row = idx8 >> 12;
        const unsigned int col = idx8 & 4095u;
        int ti; size_t soff;
        if (row < 4096u) {
            ti = (col < 2048u) ? 0 : 1;
            soff = (size_t)row * 2048 + (col & 2047u);
        } else {
            const unsigned int wrow = row - 4096u;
            const int gate = (int)(wrow >> 11);
            ti = (col < 2048u) ? (2 + gate) : (6 + gate);
            soff = (size_t)(wrow & 2047u) * 2048 + (col & 2047u);
        }
        *reinterpret_cast<ushort8_t*>(dst + idx8) = cvt_or_copy8(srcs.p[ti], soff, isF32);
    }
}

// ---------------------------------------------------------------------------
// Cooperative fused convert + GEMM + LSTM.
// ---------------------------------------------------------------------------
struct GemmArgs {
    unsigned short* conv;
    const unsigned int* Xraw;
    SrcPtrs sp;
    const void* bi0; const void* bi1; const void* bi2; const void* bi3;
    const void* Cin;
    void* outp;
    int coop;
};

#define GLL(SRC, DST) \
  __builtin_amdgcn_global_load_lds( \
      (const __attribute__((address_space(1))) void*)(SRC), \
      (__attribute__((address_space(3))) void*)(DST), 16, 0, 0)

#define STAGE_A(A0, A1, KOFF, BUF, KS) do { \
    GLL((A0) + (KOFF), lds + ((BUF) * 2 + (KS)) * 16384 + wvOff); \
    GLL((A1) + (KOFF), lds + ((BUF) * 2 + (KS)) * 16384 + 8192 + wvOff); \
  } while (0)

#define STAGE_B(B0, B1, KOFF, BUF, KS) do { \
    GLL((B0) + (KOFF), lds + 65536 + ((BUF) * 2 + (KS)) * 16384 + wvOff); \
    GLL((B1) + (KOFF), lds + 65536 + ((BUF) * 2 + (KS)) * 16384 + 8192 + wvOff); \
  } while (0)

// Phase: {ds_read frags | stage 1 half | barrier | lgkmcnt(0) | setprio(1)
//         16 MFMA | setprio(0) | [vmcnt(4)] | barrier}
#define PHASE(BUF, KS, MH, DOB, STAGE_STMT, DOVM) \
  { \
    const char* aSlot_ = lds + ((BUF) * 2 + (KS)) * 16384 + (MH) * 4096; \
    _Pragma("unroll") \
    for (int i_ = 0; i_ < 4; ++i_) \
      af[i_] = *reinterpret_cast<const bf16x8_t*>(aSlot_ + aoff[i_]); \
    if (DOB) { \
      const char* bSlot_ = lds + 65536 + ((BUF) * 2 + (KS)) * 16384; \
      _Pragma("unroll") \
      for (int i_ = 0; i_ < 4; ++i_) \
        bw[i_] = *reinterpret_cast<const bf16x8_t*>(bSlot_ + boff[i_]); \
    } \
    STAGE_STMT; \
    __builtin_amdgcn_s_barrier(); \
    asm volatile("s_waitcnt lgkmcnt(0)" ::: "memory"); \
    __builtin_amdgcn_s_setprio(1); \
    _Pragma("unroll") \
    for (int mi_ = 0; mi_ < 4; ++mi_) \
      _Pragma("unroll") \
      for (int ni_ = 0; ni_ < 4; ++ni_) \
        acc[(MH) * 4 + mi_][ni_] = __builtin_amdgcn_mfma_f32_16x16x32_bf16( \
            af[mi_], bw[ni_], acc[(MH) * 4 + mi_][ni_], 0, 0, 0); \
    __builtin_amdgcn_s_setprio(0); \
    if (DOVM) asm volatile("s_waitcnt vmcnt(4)" ::: "memory"); \
    __builtin_amdgcn_s_barrier(); \
  }

__global__ __launch_bounds__(512, 2) void gates_gemm_fast(GemmArgs A)
{
    __shared__ __align__(16) char lds[131072];   // A: 4x16K, B: 4x16K

    const int tid = threadIdx.x;
    // 256 blocks. XCD = orig%8 (round-robin). All 8 consumer blocks of W
    // panel bn land on XCD bn%8; each block does bm and bm+8 at the SAME bn.
    const int orig = blockIdx.x;              // 0..255
    const int xq   = orig & 7;
    const int j    = orig >> 3;               // 0..31
    const int bn   = xq + ((j & 3) << 3);     // H-column tile (64 cols), 0..31
    const int bm   = j >> 2;                  // M tile, 0..7; +8 = second tile

    const int isF32 = detect_f32(A.Xraw, tid & 63);

    // ---- Phase 0 (coop): convert. W panel bn rows p=bm*32..+32 (this block's
    // 1/8 share -> written on this XCD's L2); A rows orig*16..+16.
    if (A.coop) {
        const int col  = tid * 8;             // 0..4088
        const int half = (col >= 2048);
        const int colh = col & 2047;
#pragma unroll 1
        for (int p0 = 0; p0 < 32; ++p0) {
            const int p   = bm * 32 + p0;
            const int g   = p >> 6;
            const int rIn = bn * 64 + (p & 63);     // row within gate matrix
            const int wrow = g * 2048 + rIn;
            *reinterpret_cast<ushort8_t*>(A.conv + CONV_W_ELS + (size_t)wrow * 4096 + col) =
                cvt_or_copy8(A.sp.p[(half ? 6 : 2) + g], (size_t)rIn * 2048 + colh, isF32);
        }
#pragma unroll 1
        for (int r0 = 0; r0 < 16; ++r0) {
            const int r = orig * 16 + r0;
            *reinterpret_cast<ushort8_t*>(A.conv + (size_t)r * 4096 + col) =
                cvt_or_copy8(A.sp.p[half ? 1 : 0], (size_t)r * 2048 + colh, isF32);
        }
        cg::this_grid().sync();
    }

    // ---- Phase 1: GEMM + LSTM.
    const char* Ab = (const char*)A.conv;
    const char* Wb = (const char*)(A.conv + CONV_W_ELS);

    const int o0   = tid << 4;
    const int l0   = o0 ^ (((o0 >> 7) & 3) << 4);
    const int srow = l0 >> 6;                 // 0..127
    const int skb  = l0 & 63;
    const char* pA0 = Ab + ((size_t)(bm * 256 + srow)) * 8192 + skb;
    const char* pA1 = pA0 + (size_t)128 * 8192;
    const int br1 = srow + 128;
    const char* pB0 = Wb + ((size_t)((srow >> 6) * 2048 + bn * 64 + (srow & 63))) * 8192 + skb;
    const char* pB1 = Wb + ((size_t)((br1  >> 6) * 2048 + bn * 64 + (br1  & 63))) * 8192 + skb;

    const int waveU = __builtin_amdgcn_readfirstlane(tid >> 6);
    const int wvOff = waveU * 1024;
    const int lane = tid & 63;
    const int lr   = lane & 15;
    const int quad = lane >> 4;
    const int wid  = tid >> 6;
    const int wr   = wid >> 2;                // 0..1  (M half)
    const int wc   = wid & 3;                 // 0..3  (16-col quarter)

    int aoff[4], boff[4];
#pragma unroll
    for (int i = 0; i < 4; ++i) {
        int xa = (wr * 128 + i * 16 + lr) * 64 + quad * 16;
        aoff[i] = xa ^ (((xa >> 7) & 3) << 4);
        int xb = (i * 64 + wc * 16 + lr) * 64 + quad * 16;
        boff[i] = xb ^ (((xb >> 7) & 3) << 4);
    }

    // Bias + tile-1 C prefetch (issued BEFORE prologue stages: the prologue
    // vmcnt(4) drains them for free; epilogue-1 then reads registers).
    const int colH = bn * 64 + wc * 16 + lr;
    float bvv[4];
    bvv[0] = isF32 ? ((const float*)A.bi0)[colH] : __bfloat162float(((const __hip_bfloat16*)A.bi0)[colH]);
    bvv[1] = isF32 ? ((const float*)A.bi1)[colH] : __bfloat162float(((const __hip_bfloat16*)A.bi1)[colH]);
    bvv[2] = isF32 ? ((const float*)A.bi2)[colH] : __bfloat162float(((const __hip_bfloat16*)A.bi2)[colH]);
    bvv[3] = isF32 ? ((const float*)A.bi3)[colH] : __bfloat162float(((const __hip_bfloat16*)A.bi3)[colH]);

    float c1[32], c2[32];
#pragma unroll
    for (int a8 = 0; a8 < 8; ++a8)
#pragma unroll
        for (int r = 0; r < 4; ++r) {
            const int rowB = bm * 256 + wr * 128 + (a8 >> 2) * 64 + (a8 & 3) * 16 + quad * 4 + r;
            const size_t idx = (size_t)rowB * K_DIM + colH;
            c1[a8 * 4 + r] = isF32 ? ((const float*)A.Cin)[idx]
                                   : bf_bits2f(((const unsigned short*)A.Cin)[idx]);
        }

    floatx4_t acc[8][4];
#pragma unroll
    for (int a = 0; a < 8; ++a)
#pragma unroll
        for (int g = 0; g < 4; ++g)
            acc[a][g] = (floatx4_t){0.f, 0.f, 0.f, 0.f};

    // Prologue: tile0 (k0,k1) + tile1 (k0); vmcnt(4) => C1 + tile0 landed.
    STAGE_A(pA0, pA1, 0, 0, 0);   STAGE_B(pB0, pB1, 0, 0, 0);
    STAGE_A(pA0, pA1, 64, 0, 1);  STAGE_B(pB0, pB1, 64, 0, 1);
    STAGE_A(pA0, pA1, 128, 1, 0); STAGE_B(pB0, pB1, 128, 1, 0);
    asm volatile("s_waitcnt vmcnt(4)" ::: "memory");
    __builtin_amdgcn_s_barrier();

    auto epilogue = [&](int bmE, float (&cr)[32]) {
#pragma unroll
        for (int a8 = 0; a8 < 8; ++a8) {
            const int rowBase = bmE * 256 + wr * 128 + (a8 >> 2) * 64 + (a8 & 3) * 16 + quad * 4;
#pragma unroll
            for (int r = 0; r < 4; ++r) {
                const size_t idx = (size_t)(rowBase + r) * K_DIM + colH;
                const float gi = acc[a8][0][r] + bvv[0];
                const float go = acc[a8][1][r] + bvv[1];
                const float gf = acc[a8][2][r] + bvv[2];
                const float gc = acc[a8][3][r] + bvv[3];
                const float it = sigmoid_f(gi);
                const float ot = sigmoid_f(go);
                const float ft = sigmoid_f(gf);
                const float ct = tanh_f(gc);
                const float nc = ft * cr[a8 * 4 + r] + it * ct;
                const float nh = ot * tanh_f(nc);
                if (isF32) {
                    ((float*)A.outp)[idx] = nh;
                    ((float*)A.outp)[(size_t)BHT + idx] = nc;
                } else {
                    ((unsigned short*)A.outp)[idx] = f2bf_bits(nh);
                    ((unsigned short*)A.outp)[(size_t)BHT + idx] = f2bf_bits(nc);
                }
            }
        }
    };

    // Steady state per iter (t=2i in buf0, t+1 in buf1): P1..P8 as verified.
    // TILE-1 FINAL ITER: P3..P8's stages (base-shifted) ARE tile-2's prologue
    // into {b0k0,b0k1,b1k0}. P8's in-loop vmcnt(4) already leaves only b1k0
    // outstanding, and every slot's reader sits after a later vmcnt(4) with
    // >=8 younger ops -> NO inter-tile drain or barrier needed; waves flow
    // from P8 into C2-prefetch/epilogue-1 while t2 staging is in flight.
    bf16x8_t af[4], bw[4];
#pragma unroll 1
    for (int it2 = 0; it2 < NTILE / 2; ++it2) {
        const int kt = it2 * 256;
        const bool lastI = (it2 == NTILE / 2 - 1);
        const char* nA0 = lastI ? (pA0 + (ASHIFT - 8192)) : pA0;
        const char* nA1 = lastI ? (pA1 + (ASHIFT - 8192)) : pA1;
        const char* nB0 = lastI ? (pB0 - 8192) : pB0;
        const char* nB1 = lastI ? (pB1 - 8192) : pB1;
        PHASE(0, 0, 0, 1, STAGE_A(pA0, pA1, kt + 192, 1, 1), 0)
        PHASE(0, 0, 1, 0, STAGE_B(pB0, pB1, kt + 192, 1, 1), 0)
        PHASE(0, 1, 0, 1, STAGE_A(nA0, nA1, kt + 256, 0, 0), 0)
        PHASE(0, 1, 1, 0, STAGE_B(nB0, nB1, kt + 256, 0, 0), 1)
        PHASE(1, 0, 0, 1, STAGE_A(nA0, nA1, kt + 320, 0, 1), 0)
        PHASE(1, 0, 1, 0, STAGE_B(nB0, nB1, kt + 320, 0, 1), 0)
        PHASE(1, 1, 0, 1, STAGE_A(nA0, nA1, kt + 384, 1, 0), 0)
        PHASE(1, 1, 1, 0, STAGE_B(nB0, nB1, kt + 384, 1, 0), 1)
    }

    // Tile-2 C prefetch (hidden under epilogue-1 + t2 K-loop), then
    // epilogue-1 from registers, acc re-zero; straight into tile-2.
#pragma unroll
    for (int a8 = 0; a8 < 8; ++a8)
#pragma unroll
        for (int r = 0; r < 4; ++r) {
            const int rowB = (bm + 8) * 256 + wr * 128 + (a8 >> 2) * 64 + (a8 & 3) * 16 + quad * 4 + r;
            const size_t idx = (size_t)rowB * K_DIM + colH;
            c2[a8 * 4 + r] = isF32 ? ((const float*)A.Cin)[idx]
                                   : bf_bits2f(((const unsigned short*)A.Cin)[idx]);
        }
    epilogue(bm, c1);
#pragma unroll
    for (int a = 0; a < 8; ++a)
#pragma unroll
        for (int g = 0; g < 4; ++g)
            acc[a][g] = (floatx4_t){0.f, 0.f, 0.f, 0.f};

    // Tile-2 K-loop (A bases +ASHIFT; B panel identical -> L2-hot). Final-iter
    // stages read harmless in-bounds garbage (<=8.5KB past W end; 64KB pad).
    const char* qA0 = pA0 + ASHIFT;
    const char* qA1 = pA1 + ASHIFT;
#pragma unroll 1
    for (int it2 = 0; it2 < NTILE / 2; ++it2) {
        const int kt = it2 * 256;
        PHASE(0, 0, 0, 1, STAGE_A(qA0, qA1, kt + 192, 1, 1), 0)
        PHASE(0, 0, 1, 0, STAGE_B(pB0, pB1, kt + 192, 1, 1), 0)
        PHASE(0, 1, 0, 1, STAGE_A(qA0, qA1, kt + 256, 0, 0), 0)
        PHASE(0, 1, 1, 0, STAGE_B(pB0, pB1, kt + 256, 0, 0), 1)
        PHASE(1, 0, 0, 1, STAGE_A(qA0, qA1, kt + 320, 0, 1), 0)
        PHASE(1, 0, 1, 0, STAGE_B(pB0, pB1, kt + 320, 0, 1), 0)
        PHASE(1, 1, 0, 1, STAGE_A(qA0, qA1, kt + 384, 1, 0), 0)
        PHASE(1, 1, 1, 0, STAGE_B(pB0, pB1, kt + 384, 1, 0), 1)
    }
    asm volatile("s_waitcnt vmcnt(0)" ::: "memory");  // drain garbage stages
    epilogue(bm + 8, c2);
}

// ---------------------------------------------------------------------------
// Slow fallback GEMM (verified earlier): ds_write staging + in-kernel convert.
// ---------------------------------------------------------------------------
__global__ __launch_bounds__(256) void gates_gemm_slow(
    const void* __restrict__ X, const void* __restrict__ Hm,
    const void* __restrict__ Wx0, const void* __restrict__ Wx1,
    const void* __restrict__ Wx2, const void* __restrict__ Wx3,
    const void* __restrict__ Wh0, const void* __restrict__ Wh1,
    const void* __restrict__ Wh2, const void* __restrict__ Wh3,
    const void* __restrict__ bi0, const void* __restrict__ bi1,
    const void* __restrict__ bi2, const void* __restrict__ bi3,
    const int* __restrict__ flagp, int m0,
    __hip_bfloat16* __restrict__ gates)
{
    __shared__ __align__(16) char lds[16384];
    const int isF32 = *flagp;
    const int esz   = isF32 ? 4 : 2;

    const int tid     = threadIdx.x;
    const int bm      = blockIdx.y;
    const int bn      = blockIdx.x;
    const int gate    = bn >> 4;
    const int nInGate = (bn & 15) << 7;

    const void* Wx = (gate == 0) ? Wx0 : (gate == 1) ? Wx1 : (gate == 2) ? Wx2 : Wx3;
    const void* Wh = (gate == 0) ? Wh0 : (gate == 1) ? Wh1 : (gate == 2) ? Wh2 : Wh3;
    const void* bs = (gate == 0) ? bi0 : (gate == 1) ? bi1 : (gate == 2) ? bi2 : bi3;

    const int ldRow = tid >> 2;
    const int sub   = tid & 3;
    const size_t rowStride = (size_t)K_DIM * esz;
    const size_t rowHalf   = 64 * rowStride;
    const char* aG  = (const char*)X  + (size_t)(m0 + bm * 128 + ldRow) * rowStride + (size_t)sub * 8 * esz;
    const char* hG  = (const char*)Hm + (size_t)(m0 + bm * 128 + ldRow) * rowStride + (size_t)sub * 8 * esz;
    const char* wxG = (const char*)Wx + (size_t)(nInGate + ldRow) * rowStride + (size_t)sub * 8 * esz;
    const char* whG = (const char*)Wh + (size_t)(nInGate + ldRow) * rowStride + (size_t)sub * 8 * esz;

    char* const dA0 = lds + tid * 16;
    char* const dA1 = lds + 4096 + tid * 16;
    char* const dB0 = lds + 8192 + tid * 16;
    char* const dB1 = lds + 12288 + tid * 16;
    const char* const AsB = lds;
    const char* const BsB = lds + 8192;

    const int lane = tid & 63;
    const int wave = tid >> 6;
    const int wm   = (wave & 1) << 6;
    const int wn   = (wave >> 1) << 6;
    const int lr   = lane & 15;
    const int quad = lane >> 4;

    int aOff[4], bOff[4];
#pragma unroll
    for (int i = 0; i < 4; ++i) {
        aOff[i] = ((wm + i * 16 + lr) * 32 + quad * 8) * 2;
        bOff[i] = ((wn + i * 16 + lr) * 32 + quad * 8) * 2;
    }

    floatx4_t acc[4][4];
#pragma unroll
    for (int mi = 0; mi < 4; ++mi)
#pragma unroll
        for (int ni = 0; ni < 4; ++ni)
            acc[mi][ni] = (floatx4_t){0.f, 0.f, 0.f, 0.f};

#pragma unroll 1
    for (int seg = 0; seg < 2; ++seg) {
        const char* ag = seg ? hG : aG;
        const char* bg = seg ? whG : wxG;
#pragma unroll 1
        for (int ke = 0; ke < K_DIM; ke += 32) {
            const size_t kb = (size_t)ke * esz;
            ushort8_t va0, va1, vb0, vb1;
            if (!isF32) {
                va0 = *reinterpret_cast<const ushort8_t*>(ag + kb);
                va1 = *reinterpret_cast<const ushort8_t*>(ag + rowHalf + kb);
                vb0 = *reinterpret_cast<const ushort8_t*>(bg + kb);
                vb1 = *reinterpret_cast<const ushort8_t*>(bg + rowHalf + kb);
            } else {
                const char* p; float4 f0, f1;
                p = ag + kb;           f0 = *reinterpret_cast<const float4*>(p);
                f1 = *reinterpret_cast<const float4*>(p + 16);
                va0 = (ushort8_t){f2bf_bits(f0.x), f2bf_bits(f0.y), f2bf_bits(f0.z), f2bf_bits(f0.w),
                                  f2bf_bits(f1.x), f2bf_bits(f1.y), f2bf_bits(f1.z), f2bf_bits(f1.w)};
                p = ag + rowHalf + kb; f0 = *reinterpret_cast<const float4*>(p);
                f1 = *reinterpret_cast<const float4*>(p + 16);
                va1 = (ushort8_t){f2bf_bits(f0.x), f2bf_bits(f0.y), f2bf_bits(f0.z), f2bf_bits(f0.w),
                                  f2bf_bits(f1.x), f2bf_bits(f1.y), f2bf_bits(f1.z), f2bf_bits(f1.w)};
                p = bg + kb;           f0 = *reinterpret_cast<const float4*>(p);
                f1 = *reinterpret_cast<const float4*>(p + 16);
                vb0 = (ushort8_t){f2bf_bits(f0.x), f2bf_bits(f0.y), f2bf_bits(f0.z), f2bf_bits(f0.w),
                                  f2bf_bits(f1.x), f2bf_bits(f1.y), f2bf_bits(f1.z), f2bf_bits(f1.w)};
                p = bg + rowHalf + kb; f0 = *reinterpret_cast<const float4*>(p);
                f1 = *reinterpret_cast<const float4*>(p + 16);
                vb1 = (ushort8_t){f2bf_bits(f0.x), f2bf_bits(f0.y), f2bf_bits(f0.z), f2bf_bits(f0.w),
                                  f2bf_bits(f1.x), f2bf_bits(f1.y), f2bf_bits(f1.z), f2bf_bits(f1.w)};
            }
            __syncthreads();
            *reinterpret_cast<ushort8_t*>(dA0) = va0;
            *reinterpret_cast<ushort8_t*>(dA1) = va1;
            *reinterpret_cast<ushort8_t*>(dB0) = vb0;
            *reinterpret_cast<ushort8_t*>(dB1) = vb1;
            __syncthreads();

            bf16x8_t af[4], bwv[4];
#pragma unroll
            for (int i = 0; i < 4; ++i) af[i] = *reinterpret_cast<const bf16x8_t*>(AsB + aOff[i]);
#pragma unroll
            for (int i = 0; i < 4; ++i) bwv[i] = *reinterpret_cast<const bf16x8_t*>(BsB + bOff[i]);
#pragma unroll
            for (int mi = 0; mi < 4; ++mi)
#pragma unroll
                for (int ni = 0; ni < 4; ++ni)
                    acc[mi][ni] = __builtin_amdgcn_mfma_f32_16x16x32_bf16(
                        af[mi], bwv[ni], acc[mi][ni], 0, 0, 0);
        }
    }

    float bv[4];
#pragma unroll
    for (int ni = 0; ni < 4; ++ni) {
        const int col = nInGate + wn + ni * 16 + lr;
        bv[ni] = isF32 ? ((const float*)bs)[col]
                       : __bfloat162float(((const __hip_bfloat16*)bs)[col]);
    }
#pragma unroll
    for (int mi = 0; mi < 4; ++mi) {
        const int rowBase = bm * 128 + wm + mi * 16 + quad * 4;
#pragma unroll
        for (int ni = 0; ni < 4; ++ni) {
            const size_t colBase = (size_t)gate * 2048 + nInGate + wn + ni * 16 + lr;
#pragma unroll
            for (int r = 0; r < 4; ++r)
                gates[(size_t)(rowBase + r) * NG + colBase] =
                    __float2bfloat16(acc[mi][ni][r] + bv[ni]);
        }
    }
}

// ---------------------------------------------------------------------------
// Pointwise LSTM combine (fallback path only).
// ---------------------------------------------------------------------------
__global__ __launch_bounds__(256) void lstm_pointwise_kernel(
    const unsigned short* __restrict__ gates,
    const void* __restrict__ Cin,
    void* __restrict__ out,
    const int* __restrict__ flagp, int m0)
{
    const int isF32 = *flagp;
    const int lidx = (blockIdx.x * 256 + threadIdx.x) * 4;
    const int b = lidx >> 11;
    const int j = lidx & 2047;
    const unsigned short* g = gates + (size_t)b * NG + j;
    const size_t gidx = (size_t)m0 * 2048 + (size_t)lidx;

    const ushort4 ui = *reinterpret_cast<const ushort4*>(g);
    const ushort4 uo = *reinterpret_cast<const ushort4*>(g + 2048);
    const ushort4 uf = *reinterpret_cast<const ushort4*>(g + 4096);
    const ushort4 uc = *reinterpret_cast<const ushort4*>(g + 6144);
    const float gi[4] = {bf_bits2f(ui.x), bf_bits2f(ui.y), bf_bits2f(ui.z), bf_bits2f(ui.w)};
    const float go[4] = {bf_bits2f(uo.x), bf_bits2f(uo.y), bf_bits2f(uo.z), bf_bits2f(uo.w)};
    const float gf[4] = {bf_bits2f(uf.x), bf_bits2f(uf.y), bf_bits2f(uf.z), bf_bits2f(uf.w)};
    const float gc[4] = {bf_bits2f(uc.x), bf_bits2f(uc.y), bf_bits2f(uc.z), bf_bits2f(uc.w)};

    float cv[4];
    if (isF32) {
        const float4 c4 = *reinterpret_cast<const float4*>((const float*)Cin + gidx);
        cv[0] = c4.x; cv[1] = c4.y; cv[2] = c4.z; cv[3] = c4.w;
    } else {
        const ushort4 u = *reinterpret_cast<const ushort4*>((const unsigned short*)Cin + gidx);
        cv[0] = bf_bits2f(u.x); cv[1] = bf_bits2f(u.y);
        cv[2] = bf_bits2f(u.z); cv[3] = bf_bits2f(u.w);
    }

    float nh[4], nc[4];
#pragma unroll
    for (int k = 0; k < 4; ++k) {
        const float it = sigmoid_f(gi[k]);
        const float ot = sigmoid_f(go[k]);
        const float ft = sigmoid_f(gf[k]);
        const float ct = tanh_f(gc[k]);
        nc[k] = ft * cv[k] + it * ct;
        nh[k] = ot * tanh_f(nc[k]);
    }

    if (isF32) {
        float* oH = (float*)out;
        float* oC = oH + (size_t)BHT;
        *reinterpret_cast<float4*>(oH + gidx) = make_float4(nh[0], nh[1], nh[2], nh[3]);
        *reinterpret_cast<float4*>(oC + gidx) = make_float4(nc[0], nc[1], nc[2], nc[3]);
    } else {
        unsigned short* oH = (unsigned short*)out;
        unsigned short* oC = oH + (size_t)BHT;
        *reinterpret_cast<ushort4*>(oH + gidx) =
            make_ushort4(f2bf_bits(nh[0]), f2bf_bits(nh[1]), f2bf_bits(nh[2]), f2bf_bits(nh[3]));
        *reinterpret_cast<ushort4*>(oC + gidx) =
            make_ushort4(f2bf_bits(nc[0]), f2bf_bits(nc[1]), f2bf_bits(nc[2]), f2bf_bits(nc[3]));
    }
}

extern "C" void kernel_launch(void* const* d_in, const int* in_sizes, int n_in,
                              void* d_out, int out_size, void* d_ws, size_t ws_size,
                              hipStream_t stream) {
    (void)in_sizes; (void)n_in; (void)out_size;
    const void* X   = d_in[0];
    const void* Hm  = d_in[1];
    const void* C   = d_in[2];
    const void* Wxi = d_in[3];
    const void* Wxo = d_in[4];
    const void* Wxf = d_in[5];
    const void* Wxc = d_in[6];
    const void* bi  = d_in[7];
    const void* bo  = d_in[8];
    const void* bfp = d_in[9];
    const void* bc  = d_in[10];
    const void* Whi = d_in[11];
    const void* Who = d_in[12];
    const void* Whf = d_in[13];
    const void* Whc = d_in[14];

    const dim3 blk(256);

    if (ws_size >= FAST_NEED) {
        unsigned short* conv = (unsigned short*)d_ws;

        SrcPtrs sp;
        sp.p[0] = X;  sp.p[1] = Hm;
        sp.p[2] = Wxi; sp.p[3] = Wxo; sp.p[4] = Wxf; sp.p[5] = Wxc;
        sp.p[6] = Whi; sp.p[7] = Who; sp.p[8] = Whf; sp.p[9] = Whc;

        GemmArgs ga;
        ga.conv = conv; ga.Xraw = (const unsigned int*)X; ga.sp = sp;
        ga.bi0 = bi; ga.bi1 = bo; ga.bi2 = bfp; ga.bi3 = bc;
        ga.Cin = C; ga.outp = d_out; ga.coop = 1;

        void* params[] = { &ga };
        hipError_t e = hipLaunchCooperativeKernel(
            (void*)gates_gemm_fast, dim3(256), dim3(512), params, 0, stream);
        if (e != hipSuccess) {
            // Non-coop fallback: split convert, then GEMM without phase 0.
            convert_kernel<<<dim3(3072), blk, 0, stream>>>(sp, conv);
            ga.coop = 0;
            gates_gemm_fast<<<dim3(256), dim3(512), 0, stream>>>(ga);
        }
    } else {
        const size_t flagOff = (ws_size - 4) & ~(size_t)15;
        int* flag = (int*)((char*)d_ws + flagOff);
        dtype_probe_kernel<<<1, 64, 0, stream>>>((const unsigned int*)X, flag);

        __hip_bfloat16* gates = (__hip_bfloat16*)d_ws;
        int rows = B_DIM;
        while ((size_t)rows * NG * 2 > flagOff && rows > 128) rows >>= 1;
        for (int m0 = 0; m0 < B_DIM; m0 += rows) {
            gates_gemm_slow<<<dim3(64, rows / 128), blk, 0, stream>>>(
                X, Hm, Wxi, Wxo, Wxf, Wxc, Whi, Who, Whf, Whc,
                bi, bo, bfp, bc, flag, m0, gates);
            lstm_pointwise_kernel<<<dim3(rows * 2048 / 1024), blk, 0, stream>>>(
                (const unsigned short*)gates, C, d_out, flag, m0);
        }
    }
}

// Round 6
// 523.728 us; speedup vs baseline: 1.1446x; 1.1446x over previous
//
#include <hip/hip_runtime.h>
#include <hip/hip_bf16.h>
#include <cstdint>

// LSTMCell B=4096, IN=H=2048. Fast path: convert (batched-MLP, full occupancy)
// -> persistent fused GEMM (256 blocks x 2 tiles, 8-phase schedule, T2 swizzle
// + counted vmcnt + setprio) + LSTM pointwise epilogue with C reg-prefetch.
// R5 lessons: never put streaming phases inside the 1-block/CU GEMM (8 waves
// can't hide latency); fixed harness overhead ~131us regardless of launches.
// Small-ws fallback: probe + ds_write GEMM + separate pointwise.

#define B_DIM 4096
#define K_DIM 2048            // IN == H
#define NG    8192            // 4*H
#define BHT   (B_DIM * K_DIM) // B*H elements per output tensor

// ws element-layout (bf16 elements) for the fast path:
//   A [4096][4096] = [X | H] rows, at 0                  (16M els, 32 MB)
//   W [8192][4096] = [Wx_g | Wh_g] row g*2048+j, at 16M  (32M els, 64 MB)
#define CONV_W_ELS  (16u << 20)
#define CONV_TOTAL  (48u << 20)             // 48M els = 96 MB
#define FAST_NEED   ((size_t)CONV_TOTAL * 2 + 65536)  // 96 MB + pad (overstage reads)

#define NTILE 64              // K tiles: 4096 / 64
#define ASHIFT ((ptrdiff_t)8 * 256 * 8192)  // A base delta bm -> bm+8 (16 MB)

using bf16x8_t  = __attribute__((ext_vector_type(8))) __bf16;
using floatx4_t = __attribute__((ext_vector_type(4))) float;
using ushort8_t = __attribute__((ext_vector_type(8))) unsigned short;

__device__ __forceinline__ float bf_bits2f(unsigned short u) {
    return __builtin_bit_cast(float, ((unsigned int)u) << 16);
}
__device__ __forceinline__ unsigned short f2bf_bits(float f) {
    return __builtin_bit_cast(unsigned short, __float2bfloat16(f));
}
__device__ __forceinline__ float sigmoid_f(float x) {
    return 1.0f / (1.0f + __expf(-x));
}
__device__ __forceinline__ float tanh_f(float x) {
    float ax = fabsf(x);
    float e  = __expf(-2.0f * ax);
    float t  = (1.0f - e) / (1.0f + e);
    return copysignf(t, x);
}

struct SrcPtrs { const void* p[10]; };  // X,H,Wx0..3,Wh0..3

// Per-wave dtype detect from raw X words.
__device__ __forceinline__ int detect_f32(const unsigned int* X, int lane) {
    const unsigned int w = X[lane];
    const unsigned short hi = (unsigned short)(w >> 16);
    const unsigned short lo = (unsigned short)(w & 0xFFFFu);
    auto sane = [](unsigned short h) -> int {
        const int e = (h >> 7) & 0xFF;
        return (e >= 90 && e <= 140) || ((h & 0x7FFF) == 0);
    };
    const unsigned long long bh = __ballot(sane(hi));
    const unsigned long long bl = __ballot(sane(lo));
    const int cnt = __popcll(bh) + __popcll(bl);  // bf16 ~128, fp32 ~77
    return (cnt >= 112) ? 0 : 1;
}

// ---------------------------------------------------------------------------
// Dtype probe (fallback path only).
// ---------------------------------------------------------------------------
__global__ void dtype_probe_kernel(const unsigned int* __restrict__ X,
                                   int* __restrict__ flag) {
    const int f = detect_f32(X, threadIdx.x & 63);
    if (threadIdx.x == 0) *flag = f;
}

// ---------------------------------------------------------------------------
// Convert: build concat layout. Each thread handles 2 far-apart 8-el chunks
// with all source loads batched (2x MLP). Exact grid: 12288 x 256.
// A 2048-el chunk covers exactly one half-row -> uniform source per chunk.
// ---------------------------------------------------------------------------
__device__ __forceinline__ void conv_locate(unsigned int idx8, int& ti, size_t& soff) {
    const unsigned int row = idx8 >> 12;      // dest row (4096 els each)
    const unsigned int col = idx8 & 4095u;
    if (row < 4096u) {                        // A region: [X | H]
        ti = (col < 2048u) ? 0 : 1;
        soff = (size_t)row * 2048 + (col & 2047u);
    } else {                                  // W region: [Wx_g | Wh_g]
        const unsigned int wrow = row - 4096u;
        const int g = (int)(wrow >> 11);
        ti = (col < 2048u) ? (2 + g) : (6 + g);
        soff = (size_t)(wrow & 2047u) * 2048 + (col & 2047u);
    }
}

__global__ __launch_bounds__(256) void convert_kernel(
    SrcPtrs srcs, unsigned short* __restrict__ dst)
{
    const int isF32 = detect_f32((const unsigned int*)srcs.p[0], threadIdx.x & 63);
    const unsigned int t  = blockIdx.x * 256u + threadIdx.x;
    const unsigned int ia = t * 8u;
    const unsigned int ib = ia + (CONV_TOTAL / 2);

    int tia, tib; size_t sa, sb;
    conv_locate(ia, tia, sa);
    conv_locate(ib, tib, sb);

    ushort8_t va, vb;
    if (isF32) {
        const float* pa = (const float*)srcs.p[tia] + sa;
        const float* pb = (const float*)srcs.p[tib] + sb;
        const float4 a0 = *reinterpret_cast<const float4*>(pa);
        const float4 a1 = *reinterpret_cast<const float4*>(pa + 4);
        const float4 b0 = *reinterpret_cast<const float4*>(pb);
        const float4 b1 = *reinterpret_cast<const float4*>(pb + 4);
        va = (ushort8_t){f2bf_bits(a0.x), f2bf_bits(a0.y), f2bf_bits(a0.z), f2bf_bits(a0.w),
                         f2bf_bits(a1.x), f2bf_bits(a1.y), f2bf_bits(a1.z), f2bf_bits(a1.w)};
        vb = (ushort8_t){f2bf_bits(b0.x), f2bf_bits(b0.y), f2bf_bits(b0.z), f2bf_bits(b0.w),
                         f2bf_bits(b1.x), f2bf_bits(b1.y), f2bf_bits(b1.z), f2bf_bits(b1.w)};
    } else {
        va = *reinterpret_cast<const ushort8_t*>((const unsigned short*)srcs.p[tia] + sa);
        vb = *reinterpret_cast<const ushort8_t*>((const unsigned short*)srcs.p[tib] + sb);
    }
    *reinterpret_cast<ushort8_t*>(dst + ia) = va;
    *reinterpret_cast<ushort8_t*>(dst + ib) = vb;
}

// ---------------------------------------------------------------------------
// Persistent fused GEMM+LSTM. 256 blocks, 2 tiles each (bm and bm+8, same bn).
// Per tile: 256 rows x 64 H-cols x 4 gates, BK=64, 512 thr = 8 waves (2Mx4N),
// 8-phase schedule. The 4 "ni" frag slots are the 4 gates.
// ---------------------------------------------------------------------------
#define GLL(SRC, DST) \
  __builtin_amdgcn_global_load_lds( \
      (const __attribute__((address_space(1))) void*)(SRC), \
      (__attribute__((address_space(3))) void*)(DST), 16, 0, 0)

#define STAGE_A(A0, A1, KOFF, BUF, KS) do { \
    GLL((A0) + (KOFF), lds + ((BUF) * 2 + (KS)) * 16384 + wvOff); \
    GLL((A1) + (KOFF), lds + ((BUF) * 2 + (KS)) * 16384 + 8192 + wvOff); \
  } while (0)

#define STAGE_B(B0, B1, KOFF, BUF, KS) do { \
    GLL((B0) + (KOFF), lds + 65536 + ((BUF) * 2 + (KS)) * 16384 + wvOff); \
    GLL((B1) + (KOFF), lds + 65536 + ((BUF) * 2 + (KS)) * 16384 + 8192 + wvOff); \
  } while (0)

// Phase: {ds_read frags | stage 1 half | barrier | lgkmcnt(0) | setprio(1)
//         16 MFMA | setprio(0) | [vmcnt(4)] | barrier}
#define PHASE(BUF, KS, MH, DOB, STAGE_STMT, DOVM) \
  { \
    const char* aSlot_ = lds + ((BUF) * 2 + (KS)) * 16384 + (MH) * 4096; \
    _Pragma("unroll") \
    for (int i_ = 0; i_ < 4; ++i_) \
      af[i_] = *reinterpret_cast<const bf16x8_t*>(aSlot_ + aoff[i_]); \
    if (DOB) { \
      const char* bSlot_ = lds + 65536 + ((BUF) * 2 + (KS)) * 16384; \
      _Pragma("unroll") \
      for (int i_ = 0; i_ < 4; ++i_) \
        bw[i_] = *reinterpret_cast<const bf16x8_t*>(bSlot_ + boff[i_]); \
    } \
    STAGE_STMT; \
    __builtin_amdgcn_s_barrier(); \
    asm volatile("s_waitcnt lgkmcnt(0)" ::: "memory"); \
    __builtin_amdgcn_s_setprio(1); \
    _Pragma("unroll") \
    for (int mi_ = 0; mi_ < 4; ++mi_) \
      _Pragma("unroll") \
      for (int ni_ = 0; ni_ < 4; ++ni_) \
        acc[(MH) * 4 + mi_][ni_] = __builtin_amdgcn_mfma_f32_16x16x32_bf16( \
            af[mi_], bw[ni_], acc[(MH) * 4 + mi_][ni_], 0, 0, 0); \
    __builtin_amdgcn_s_setprio(0); \
    if (DOVM) asm volatile("s_waitcnt vmcnt(4)" ::: "memory"); \
    __builtin_amdgcn_s_barrier(); \
  }

__global__ __launch_bounds__(512, 2) void gates_gemm_fast(
    const unsigned short* __restrict__ conv,
    const unsigned int* __restrict__ Xraw,
    const void* __restrict__ bi0, const void* __restrict__ bi1,
    const void* __restrict__ bi2, const void* __restrict__ bi3,
    const void* __restrict__ Cin,
    void* __restrict__ outp)                  // h [4096,2048], c follows
{
    __shared__ __align__(16) char lds[131072];   // A: 4x16K, B: 4x16K

    const int tid = threadIdx.x;
    // 256 blocks. XCD = orig%8 (round-robin). All 8 consumer blocks of W
    // panel bn land on XCD bn%8; each block does bm and bm+8 at the SAME bn
    // so round-2 W reads hit L2/L3.
    const int orig = blockIdx.x;              // 0..255
    const int xq   = orig & 7;
    const int j    = orig >> 3;               // 0..31
    const int bn   = xq + ((j & 3) << 3);     // H-column tile (64 cols), 0..31
    const int bm   = j >> 2;                  // M tile, 0..7; +8 = second tile

    const int isF32 = detect_f32(Xraw, tid & 63);

    const char* Ab = (const char*)conv;
    const char* Wb = (const char*)(conv + CONV_W_ELS);

    const int o0   = tid << 4;
    const int l0   = o0 ^ (((o0 >> 7) & 3) << 4);
    const int srow = l0 >> 6;                 // 0..127
    const int skb  = l0 & 63;
    const char* pA0 = Ab + ((size_t)(bm * 256 + srow)) * 8192 + skb;
    const char* pA1 = pA0 + (size_t)128 * 8192;
    // B-tile row r: gate r>>6, W row (r>>6)*2048 + bn*64 + (r&63).
    const int br1 = srow + 128;
    const char* pB0 = Wb + ((size_t)((srow >> 6) * 2048 + bn * 64 + (srow & 63))) * 8192 + skb;
    const char* pB1 = Wb + ((size_t)((br1  >> 6) * 2048 + bn * 64 + (br1  & 63))) * 8192 + skb;

    const int waveU = __builtin_amdgcn_readfirstlane(tid >> 6);
    const int wvOff = waveU * 1024;
    const int lane = tid & 63;
    const int lr   = lane & 15;
    const int quad = lane >> 4;
    const int wid  = tid >> 6;
    const int wr   = wid >> 2;                // 0..1  (M half)
    const int wc   = wid & 3;                 // 0..3  (16-col quarter)

    int aoff[4], boff[4];
#pragma unroll
    for (int i = 0; i < 4; ++i) {
        int xa = (wr * 128 + i * 16 + lr) * 64 + quad * 16;
        aoff[i] = xa ^ (((xa >> 7) & 3) << 4);
        int xb = (i * 64 + wc * 16 + lr) * 64 + quad * 16;
        boff[i] = xb ^ (((xb >> 7) & 3) << 4);
    }

    // Bias + tile-1 C prefetch (issued BEFORE prologue stages: the prologue
    // vmcnt(4) drains them for free; epilogue-1 then reads registers).
    const int colH = bn * 64 + wc * 16 + lr;
    float bvv[4];
    bvv[0] = isF32 ? ((const float*)bi0)[colH] : __bfloat162float(((const __hip_bfloat16*)bi0)[colH]);
    bvv[1] = isF32 ? ((const float*)bi1)[colH] : __bfloat162float(((const __hip_bfloat16*)bi1)[colH]);
    bvv[2] = isF32 ? ((const float*)bi2)[colH] : __bfloat162float(((const __hip_bfloat16*)bi2)[colH]);
    bvv[3] = isF32 ? ((const float*)bi3)[colH] : __bfloat162float(((const __hip_bfloat16*)bi3)[colH]);

    float c1[32], c2[32];
#pragma unroll
    for (int a8 = 0; a8 < 8; ++a8)
#pragma unroll
        for (int r = 0; r < 4; ++r) {
            const int rowB = bm * 256 + wr * 128 + (a8 >> 2) * 64 + (a8 & 3) * 16 + quad * 4 + r;
            const size_t idx = (size_t)rowB * K_DIM + colH;
            c1[a8 * 4 + r] = isF32 ? ((const float*)Cin)[idx]
                                   : bf_bits2f(((const unsigned short*)Cin)[idx]);
        }

    floatx4_t acc[8][4];
#pragma unroll
    for (int a = 0; a < 8; ++a)
#pragma unroll
        for (int g = 0; g < 4; ++g)
            acc[a][g] = (floatx4_t){0.f, 0.f, 0.f, 0.f};

    // Prologue: tile0 (k0,k1) + tile1 (k0); vmcnt(4) => C1/bias + t0 landed
    // (youngest 4 = t1k0's stages).
    STAGE_A(pA0, pA1, 0, 0, 0);   STAGE_B(pB0, pB1, 0, 0, 0);
    STAGE_A(pA0, pA1, 64, 0, 1);  STAGE_B(pB0, pB1, 64, 0, 1);
    STAGE_A(pA0, pA1, 128, 1, 0); STAGE_B(pB0, pB1, 128, 1, 0);
    asm volatile("s_waitcnt vmcnt(4)" ::: "memory");
    __builtin_amdgcn_s_barrier();

    auto epilogue = [&](int bmE, float (&cr)[32]) {
#pragma unroll
        for (int a8 = 0; a8 < 8; ++a8) {
            const int rowBase = bmE * 256 + wr * 128 + (a8 >> 2) * 64 + (a8 & 3) * 16 + quad * 4;
#pragma unroll
            for (int r = 0; r < 4; ++r) {
                const size_t idx = (size_t)(rowBase + r) * K_DIM + colH;
                const float gi = acc[a8][0][r] + bvv[0];
                const float go = acc[a8][1][r] + bvv[1];
                const float gf = acc[a8][2][r] + bvv[2];
                const float gc = acc[a8][3][r] + bvv[3];
                const float it = sigmoid_f(gi);
                const float ot = sigmoid_f(go);
                const float ft = sigmoid_f(gf);
                const float ct = tanh_f(gc);
                const float nc = ft * cr[a8 * 4 + r] + it * ct;
                const float nh = ot * tanh_f(nc);
                if (isF32) {
                    ((float*)outp)[idx] = nh;
                    ((float*)outp)[(size_t)BHT + idx] = nc;
                } else {
                    ((unsigned short*)outp)[idx] = f2bf_bits(nh);
                    ((unsigned short*)outp)[(size_t)BHT + idx] = f2bf_bits(nc);
                }
            }
        }
    };

    // Steady state per iter (t=2i in buf0, t+1 in buf1):
    //  P1 rd buf0k0, st A(t+1,k1)->b1k1   P5 rd buf1k0, st A(t+2,k1)->b0k1
    //  P2 rd buf0k0, st B(t+1,k1)         P6 rd buf1k0, st B(t+2,k1)
    //  P3 rd buf0k1, st A(t+2,k0)->b0k0   P7 rd buf1k1, st A(t+3,k0)->b1k0
    //  P4 rd buf0k1, st B(t+2,k0); vm4    P8 rd buf1k1, st B(t+3,k0); vm4
    // W-A-R: every stage targets a slot last read >=1 barrier earlier.
    // R-A-W: vm4@P4 covers P5/P7; vm4@P8 covers next-iter P1/P3.
    // TILE-1 FINAL ITER: P3..P8's stages (base-shifted) ARE tile-2's prologue
    // into {b0k0,b0k1,b1k0}. At final P8's vm4+barrier, b0k0/b0k1 are landed
    // globally; only b1k0's 4 ops may fly, and tile-2's P4 vm4 drains them
    // before P5 reads b1k0 -> NO inter-tile drain/barrier needed (HW-validated
    // in R5). Waves flow from P8 into C2-prefetch/epilogue-1 while t2 staging
    // is in flight.
    bf16x8_t af[4], bw[4];
#pragma unroll 1
    for (int it2 = 0; it2 < NTILE / 2; ++it2) {
        const int kt = it2 * 256;
        const bool lastI = (it2 == NTILE / 2 - 1);
        const char* nA0 = lastI ? (pA0 + (ASHIFT - 8192)) : pA0;
        const char* nA1 = lastI ? (pA1 + (ASHIFT - 8192)) : pA1;
        const char* nB0 = lastI ? (pB0 - 8192) : pB0;
        const char* nB1 = lastI ? (pB1 - 8192) : pB1;
        PHASE(0, 0, 0, 1, STAGE_A(pA0, pA1, kt + 192, 1, 1), 0)
        PHASE(0, 0, 1, 0, STAGE_B(pB0, pB1, kt + 192, 1, 1), 0)
        PHASE(0, 1, 0, 1, STAGE_A(nA0, nA1, kt + 256, 0, 0), 0)
        PHASE(0, 1, 1, 0, STAGE_B(nB0, nB1, kt + 256, 0, 0), 1)
        PHASE(1, 0, 0, 1, STAGE_A(nA0, nA1, kt + 320, 0, 1), 0)
        PHASE(1, 0, 1, 0, STAGE_B(nB0, nB1, kt + 320, 0, 1), 0)
        PHASE(1, 1, 0, 1, STAGE_A(nA0, nA1, kt + 384, 1, 0), 0)
        PHASE(1, 1, 1, 0, STAGE_B(nB0, nB1, kt + 384, 1, 0), 1)
    }

    // Tile-2 C prefetch (hides under epilogue-1), epilogue-1 from registers,
    // acc re-zero; straight into tile-2.
#pragma unroll
    for (int a8 = 0; a8 < 8; ++a8)
#pragma unroll
        for (int r = 0; r < 4; ++r) {
            const int rowB = (bm + 8) * 256 + wr * 128 + (a8 >> 2) * 64 + (a8 & 3) * 16 + quad * 4 + r;
            const size_t idx = (size_t)rowB * K_DIM + colH;
            c2[a8 * 4 + r] = isF32 ? ((const float*)Cin)[idx]
                                   : bf_bits2f(((const unsigned short*)Cin)[idx]);
        }
    epilogue(bm, c1);
#pragma unroll
    for (int a = 0; a < 8; ++a)
#pragma unroll
        for (int g = 0; g < 4; ++g)
            acc[a][g] = (floatx4_t){0.f, 0.f, 0.f, 0.f};

    // Tile-2 K-loop (A bases +ASHIFT; B panel identical -> L2-hot). Final-iter
    // stages read harmless in-bounds garbage (<=8.5KB past W end; 64KB pad).
    const char* qA0 = pA0 + ASHIFT;
    const char* qA1 = pA1 + ASHIFT;
#pragma unroll 1
    for (int it2 = 0; it2 < NTILE / 2; ++it2) {
        const int kt = it2 * 256;
        PHASE(0, 0, 0, 1, STAGE_A(qA0, qA1, kt + 192, 1, 1), 0)
        PHASE(0, 0, 1, 0, STAGE_B(pB0, pB1, kt + 192, 1, 1), 0)
        PHASE(0, 1, 0, 1, STAGE_A(qA0, qA1, kt + 256, 0, 0), 0)
        PHASE(0, 1, 1, 0, STAGE_B(pB0, pB1, kt + 256, 0, 0), 1)
        PHASE(1, 0, 0, 1, STAGE_A(qA0, qA1, kt + 320, 0, 1), 0)
        PHASE(1, 0, 1, 0, STAGE_B(pB0, pB1, kt + 320, 0, 1), 0)
        PHASE(1, 1, 0, 1, STAGE_A(qA0, qA1, kt + 384, 1, 0), 0)
        PHASE(1, 1, 1, 0, STAGE_B(pB0, pB1, kt + 384, 1, 0), 1)
    }
    asm volatile("s_waitcnt vmcnt(0)" ::: "memory");  // drain garbage stages
    epilogue(bm + 8, c2);
}

// ---------------------------------------------------------------------------
// Slow fallback GEMM (verified earlier): ds_write staging + in-kernel convert.
// ---------------------------------------------------------------------------
__global__ __launch_bounds__(256) void gates_gemm_slow(
    const void* __restrict__ X, const void* __restrict__ Hm,
    const void* __restrict__ Wx0, const void* __restrict__ Wx1,
    const void* __restrict__ Wx2, const void* __restrict__ Wx3,
    const void* __restrict__ Wh0, const void* __restrict__ Wh1,
    const void* __restrict__ Wh2, const void* __restrict__ Wh3,
    const void* __restrict__ bi0, const void* __restrict__ bi1,
    const void* __restrict__ bi2, const void* __restrict__ bi3,
    const int* __restrict__ flagp, int m0,
    __hip_bfloat16* __restrict__ gates)
{
    __shared__ __align__(16) char lds[16384];
    const int isF32 = *flagp;
    const int esz   = isF32 ? 4 : 2;

    const int tid     = threadIdx.x;
    const int bm      = blockIdx.y;
    const int bn      = blockIdx.x;
    const int gate    = bn >> 4;
    const int nInGate = (bn & 15) << 7;

    const void* Wx = (gate == 0) ? Wx0 : (gate == 1) ? Wx1 : (gate == 2) ? Wx2 : Wx3;
    const void* Wh = (gate == 0) ? Wh0 : (gate == 1) ? Wh1 : (gate == 2) ? Wh2 : Wh3;
    const void* bs = (gate == 0) ? bi0 : (gate == 1) ? bi1 : (gate == 2) ? bi2 : bi3;

    const int ldRow = tid >> 2;
    const int sub   = tid & 3;
    const size_t rowStride = (size_t)K_DIM * esz;
    const size_t rowHalf   = 64 * rowStride;
    const char* aG  = (const char*)X  + (size_t)(m0 + bm * 128 + ldRow) * rowStride + (size_t)sub * 8 * esz;
    const char* hG  = (const char*)Hm + (size_t)(m0 + bm * 128 + ldRow) * rowStride + (size_t)sub * 8 * esz;
    const char* wxG = (const char*)Wx + (size_t)(nInGate + ldRow) * rowStride + (size_t)sub * 8 * esz;
    const char* whG = (const char*)Wh + (size_t)(nInGate + ldRow) * rowStride + (size_t)sub * 8 * esz;

    char* const dA0 = lds + tid * 16;
    char* const dA1 = lds + 4096 + tid * 16;
    char* const dB0 = lds + 8192 + tid * 16;
    char* const dB1 = lds + 12288 + tid * 16;
    const char* const AsB = lds;
    const char* const BsB = lds + 8192;

    const int lane = tid & 63;
    const int wave = tid >> 6;
    const int wm   = (wave & 1) << 6;
    const int wn   = (wave >> 1) << 6;
    const int lr   = lane & 15;
    const int quad = lane >> 4;

    int aOff[4], bOff[4];
#pragma unroll
    for (int i = 0; i < 4; ++i) {
        aOff[i] = ((wm + i * 16 + lr) * 32 + quad * 8) * 2;
        bOff[i] = ((wn + i * 16 + lr) * 32 + quad * 8) * 2;
    }

    floatx4_t acc[4][4];
#pragma unroll
    for (int mi = 0; mi < 4; ++mi)
#pragma unroll
        for (int ni = 0; ni < 4; ++ni)
            acc[mi][ni] = (floatx4_t){0.f, 0.f, 0.f, 0.f};

#pragma unroll 1
    for (int seg = 0; seg < 2; ++seg) {
        const char* ag = seg ? hG : aG;
        const char* bg = seg ? whG : wxG;
#pragma unroll 1
        for (int ke = 0; ke < K_DIM; ke += 32) {
            const size_t kb = (size_t)ke * esz;
            ushort8_t va0, va1, vb0, vb1;
            if (!isF32) {
                va0 = *reinterpret_cast<const ushort8_t*>(ag + kb);
                va1 = *reinterpret_cast<const ushort8_t*>(ag + rowHalf + kb);
                vb0 = *reinterpret_cast<const ushort8_t*>(bg + kb);
                vb1 = *reinterpret_cast<const ushort8_t*>(bg + rowHalf + kb);
            } else {
                const char* p; float4 f0, f1;
                p = ag + kb;           f0 = *reinterpret_cast<const float4*>(p);
                f1 = *reinterpret_cast<const float4*>(p + 16);
                va0 = (ushort8_t){f2bf_bits(f0.x), f2bf_bits(f0.y), f2bf_bits(f0.z), f2bf_bits(f0.w),
                                  f2bf_bits(f1.x), f2bf_bits(f1.y), f2bf_bits(f1.z), f2bf_bits(f1.w)};
                p = ag + rowHalf + kb; f0 = *reinterpret_cast<const float4*>(p);
                f1 = *reinterpret_cast<const float4*>(p + 16);
                va1 = (ushort8_t){f2bf_bits(f0.x), f2bf_bits(f0.y), f2bf_bits(f0.z), f2bf_bits(f0.w),
                                  f2bf_bits(f1.x), f2bf_bits(f1.y), f2bf_bits(f1.z), f2bf_bits(f1.w)};
                p = bg + kb;           f0 = *reinterpret_cast<const float4*>(p);
                f1 = *reinterpret_cast<const float4*>(p + 16);
                vb0 = (ushort8_t){f2bf_bits(f0.x), f2bf_bits(f0.y), f2bf_bits(f0.z), f2bf_bits(f0.w),
                                  f2bf_bits(f1.x), f2bf_bits(f1.y), f2bf_bits(f1.z), f2bf_bits(f1.w)};
                p = bg + rowHalf + kb; f0 = *reinterpret_cast<const float4*>(p);
                f1 = *reinterpret_cast<const float4*>(p + 16);
                vb1 = (ushort8_t){f2bf_bits(f0.x), f2bf_bits(f0.y), f2bf_bits(f0.z), f2bf_bits(f0.w),
                                  f2bf_bits(f1.x), f2bf_bits(f1.y), f2bf_bits(f1.z), f2bf_bits(f1.w)};
            }
            __syncthreads();
            *reinterpret_cast<ushort8_t*>(dA0) = va0;
            *reinterpret_cast<ushort8_t*>(dA1) = va1;
            *reinterpret_cast<ushort8_t*>(dB0) = vb0;
            *reinterpret_cast<ushort8_t*>(dB1) = vb1;
            __syncthreads();

            bf16x8_t af[4], bwv[4];
#pragma unroll
            for (int i = 0; i < 4; ++i) af[i] = *reinterpret_cast<const bf16x8_t*>(AsB + aOff[i]);
#pragma unroll
            for (int i = 0; i < 4; ++i) bwv[i] = *reinterpret_cast<const bf16x8_t*>(BsB + bOff[i]);
#pragma unroll
            for (int mi = 0; mi < 4; ++mi)
#pragma unroll
                for (int ni = 0; ni < 4; ++ni)
                    acc[mi][ni] = __builtin_amdgcn_mfma_f32_16x16x32_bf16(
                        af[mi], bwv[ni], acc[mi][ni], 0, 0, 0);
        }
    }

    float bv[4];
#pragma unroll
    for (int ni = 0; ni < 4; ++ni) {
        const int col = nInGate + wn + ni * 16 + lr;
        bv[ni] = isF32 ? ((const float*)bs)[col]
                       : __bfloat162float(((const __hip_bfloat16*)bs)[col]);
    }
#pragma unroll
    for (int mi = 0; mi < 4; ++mi) {
        const int rowBase = bm * 128 + wm + mi * 16 + quad * 4;
#pragma unroll
        for (int ni = 0; ni < 4; ++ni) {
            const size_t colBase = (size_t)gate * 2048 + nInGate + wn + ni * 16 + lr;
#pragma unroll
            for (int r = 0; r < 4; ++r)
                gates[(size_t)(rowBase + r) * NG + colBase] =
                    __float2bfloat16(acc[mi][ni][r] + bv[ni]);
        }
    }
}

// ---------------------------------------------------------------------------
// Pointwise LSTM combine (fallback path only).
// ---------------------------------------------------------------------------
__global__ __launch_bounds__(256) void lstm_pointwise_kernel(
    const unsigned short* __restrict__ gates,
    const void* __restrict__ Cin,
    void* __restrict__ out,
    const int* __restrict__ flagp, int m0)
{
    const int isF32 = *flagp;
    const int lidx = (blockIdx.x * 256 + threadIdx.x) * 4;
    const int b = lidx >> 11;
    const int j = lidx & 2047;
    const unsigned short* g = gates + (size_t)b * NG + j;
    const size_t gidx = (size_t)m0 * 2048 + (size_t)lidx;

    const ushort4 ui = *reinterpret_cast<const ushort4*>(g);
    const ushort4 uo = *reinterpret_cast<const ushort4*>(g + 2048);
    const ushort4 uf = *reinterpret_cast<const ushort4*>(g + 4096);
    const ushort4 uc = *reinterpret_cast<const ushort4*>(g + 6144);
    const float gi[4] = {bf_bits2f(ui.x), bf_bits2f(ui.y), bf_bits2f(ui.z), bf_bits2f(ui.w)};
    const float go[4] = {bf_bits2f(uo.x), bf_bits2f(uo.y), bf_bits2f(uo.z), bf_bits2f(uo.w)};
    const float gf[4] = {bf_bits2f(uf.x), bf_bits2f(uf.y), bf_bits2f(uf.z), bf_bits2f(uf.w)};
    const float gc[4] = {bf_bits2f(uc.x), bf_bits2f(uc.y), bf_bits2f(uc.z), bf_bits2f(uc.w)};

    float cv[4];
    if (isF32) {
        const float4 c4 = *reinterpret_cast<const float4*>((const float*)Cin + gidx);
        cv[0] = c4.x; cv[1] = c4.y; cv[2] = c4.z; cv[3] = c4.w;
    } else {
        const ushort4 u = *reinterpret_cast<const ushort4*>((const unsigned short*)Cin + gidx);
        cv[0] = bf_bits2f(u.x); cv[1] = bf_bits2f(u.y);
        cv[2] = bf_bits2f(u.z); cv[3] = bf_bits2f(u.w);
    }

    float nh[4], nc[4];
#pragma unroll
    for (int k = 0; k < 4; ++k) {
        const float it = sigmoid_f(gi[k]);
        const float ot = sigmoid_f(go[k]);
        const float ft = sigmoid_f(gf[k]);
        const float ct = tanh_f(gc[k]);
        nc[k] = ft * cv[k] + it * ct;
        nh[k] = ot * tanh_f(nc[k]);
    }

    if (isF32) {
        float* oH = (float*)out;
        float* oC = oH + (size_t)BHT;
        *reinterpret_cast<float4*>(oH + gidx) = make_float4(nh[0], nh[1], nh[2], nh[3]);
        *reinterpret_cast<float4*>(oC + gidx) = make_float4(nc[0], nc[1], nc[2], nc[3]);
    } else {
        unsigned short* oH = (unsigned short*)out;
        unsigned short* oC = oH + (size_t)BHT;
        *reinterpret_cast<ushort4*>(oH + gidx) =
            make_ushort4(f2bf_bits(nh[0]), f2bf_bits(nh[1]), f2bf_bits(nh[2]), f2bf_bits(nh[3]));
        *reinterpret_cast<ushort4*>(oC + gidx) =
            make_ushort4(f2bf_bits(nc[0]), f2bf_bits(nc[1]), f2bf_bits(nc[2]), f2bf_bits(nc[3]));
    }
}

extern "C" void kernel_launch(void* const* d_in, const int* in_sizes, int n_in,
                              void* d_out, int out_size, void* d_ws, size_t ws_size,
                              hipStream_t stream) {
    (void)in_sizes; (void)n_in; (void)out_size;
    const void* X   = d_in[0];
    const void* Hm  = d_in[1];
    const void* C   = d_in[2];
    const void* Wxi = d_in[3];
    const void* Wxo = d_in[4];
    const void* Wxf = d_in[5];
    const void* Wxc = d_in[6];
    const void* bi  = d_in[7];
    const void* bo  = d_in[8];
    const void* bfp = d_in[9];
    const void* bc  = d_in[10];
    const void* Whi = d_in[11];
    const void* Who = d_in[12];
    const void* Whf = d_in[13];
    const void* Whc = d_in[14];

    const dim3 blk(256);

    if (ws_size >= FAST_NEED) {
        unsigned short* conv = (unsigned short*)d_ws;

        SrcPtrs sp;
        sp.p[0] = X;  sp.p[1] = Hm;
        sp.p[2] = Wxi; sp.p[3] = Wxo; sp.p[4] = Wxf; sp.p[5] = Wxc;
        sp.p[6] = Whi; sp.p[7] = Who; sp.p[8] = Whf; sp.p[9] = Whc;

        // 12288 blocks x 256 thr x 2 chunks = 48M els.
        convert_kernel<<<dim3(12288), blk, 0, stream>>>(sp, conv);

        gates_gemm_fast<<<dim3(256), dim3(512), 0, stream>>>(
            conv, (const unsigned int*)X, bi, bo, bfp, bc, C, d_out);
    } else {
        const size_t flagOff = (ws_size - 4) & ~(size_t)15;
        int* flag = (int*)((char*)d_ws + flagOff);
        dtype_probe_kernel<<<1, 64, 0, stream>>>((const unsigned int*)X, flag);

        __hip_bfloat16* gates = (__hip_bfloat16*)d_ws;
        int rows = B_DIM;
        while ((size_t)rows * NG * 2 > flagOff && rows > 128) rows >>= 1;
        for (int m0 = 0; m0 < B_DIM; m0 += rows) {
            gates_gemm_slow<<<dim3(64, rows / 128), blk, 0, stream>>>(
                X, Hm, Wxi, Wxo, Wxf, Wxc, Whi, Who, Whf, Whc,
                bi, bo, bfp, bc, flag, m0, gates);
            lstm_pointwise_kernel<<<dim3(rows * 2048 / 1024), blk, 0, stream>>>(
                (const unsigned short*)gates, C, d_out, flag, m0);
        }
    }
}

// Round 7
// 494.775 us; speedup vs baseline: 1.2116x; 1.0585x over previous
//
#include <hip/hip_runtime.h>
#include <hip/hip_bf16.h>
#include <cstdint>

// LSTMCell B=4096, IN=H=2048. Fast path: convert (2-chunk MLP, no detect)
// -> persistent fused GEMM (256 blocks x 2 tiles, 8-phase schedule, T2 swizzle
// + counted vmcnt + setprio, no-drain inter-tile handoff) + LSTM epilogue.
// Dtype resolved on HOST from in_sizes[0] (bytes); -1 => device detect.
// R6 lesson: ~20 spare VGPRs only (acc=128 AGPR + cap 256 unified/wave at
// 8 waves/CU) — register prefetch arrays spill to scratch (+47MB writes).
// Small-ws fallback: probe + ds_write GEMM + separate pointwise.

#define B_DIM 4096
#define K_DIM 2048            // IN == H
#define NG    8192            // 4*H
#define BHT   (B_DIM * K_DIM) // B*H elements per output tensor

// ws element-layout (bf16 elements) for the fast path:
//   A [4096][4096] = [X | H] rows, at 0                  (16M els, 32 MB)
//   W [8192][4096] = [Wx_g | Wh_g] row g*2048+j, at 16M  (32M els, 64 MB)
#define CONV_W_ELS  (16u << 20)
#define CONV_TOTAL  (48u << 20)             // 48M els = 96 MB
#define FAST_NEED   ((size_t)CONV_TOTAL * 2 + 65536)  // 96 MB + pad (overstage reads)

#define NTILE 64              // K tiles: 4096 / 64
#define ASHIFT ((ptrdiff_t)8 * 256 * 8192)  // A base delta bm -> bm+8 (16 MB)

using bf16x8_t  = __attribute__((ext_vector_type(8))) __bf16;
using floatx4_t = __attribute__((ext_vector_type(4))) float;
using ushort8_t = __attribute__((ext_vector_type(8))) unsigned short;

__device__ __forceinline__ float bf_bits2f(unsigned short u) {
    return __builtin_bit_cast(float, ((unsigned int)u) << 16);
}
__device__ __forceinline__ unsigned short f2bf_bits(float f) {
    return __builtin_bit_cast(unsigned short, __float2bfloat16(f));
}
__device__ __forceinline__ float sigmoid_f(float x) {
    return 1.0f / (1.0f + __expf(-x));
}
__device__ __forceinline__ float tanh_f(float x) {
    float ax = fabsf(x);
    float e  = __expf(-2.0f * ax);
    float t  = (1.0f - e) / (1.0f + e);
    return copysignf(t, x);
}

struct SrcPtrs { const void* p[10]; };  // X,H,Wx0..3,Wh0..3

// Per-wave dtype detect from raw X words (fallback when host can't tell).
__device__ __forceinline__ int detect_f32(const unsigned int* X, int lane) {
    const unsigned int w = X[lane];
    const unsigned short hi = (unsigned short)(w >> 16);
    const unsigned short lo = (unsigned short)(w & 0xFFFFu);
    auto sane = [](unsigned short h) -> int {
        const int e = (h >> 7) & 0xFF;
        return (e >= 90 && e <= 140) || ((h & 0x7FFF) == 0);
    };
    const unsigned long long bh = __ballot(sane(hi));
    const unsigned long long bl = __ballot(sane(lo));
    const int cnt = __popcll(bh) + __popcll(bl);  // bf16 ~128, fp32 ~77
    return (cnt >= 112) ? 0 : 1;
}

// ---------------------------------------------------------------------------
// Dtype probe (small-ws fallback path only).
// ---------------------------------------------------------------------------
__global__ void dtype_probe_kernel(const unsigned int* __restrict__ X,
                                   int* __restrict__ flag) {
    const int f = detect_f32(X, threadIdx.x & 63);
    if (threadIdx.x == 0) *flag = f;
}

// ---------------------------------------------------------------------------
// Convert: build concat layout. Each thread handles 2 far-apart 8-el chunks
// with all source loads batched (2x MLP). Exact grid: 12288 x 256.
// A 2048-el chunk covers exactly one half-row -> uniform source per chunk.
// ---------------------------------------------------------------------------
__device__ __forceinline__ void conv_locate(unsigned int idx8, int& ti, size_t& soff) {
    const unsigned int row = idx8 >> 12;      // dest row (4096 els each)
    const unsigned int col = idx8 & 4095u;
    if (row < 4096u) {                        // A region: [X | H]
        ti = (col < 2048u) ? 0 : 1;
        soff = (size_t)row * 2048 + (col & 2047u);
    } else {                                  // W region: [Wx_g | Wh_g]
        const unsigned int wrow = row - 4096u;
        const int g = (int)(wrow >> 11);
        ti = (col < 2048u) ? (2 + g) : (6 + g);
        soff = (size_t)(wrow & 2047u) * 2048 + (col & 2047u);
    }
}

__global__ __launch_bounds__(256) void convert_kernel(
    SrcPtrs srcs, unsigned short* __restrict__ dst, int f32mode)
{
    const int isF32 = (f32mode >= 0) ? f32mode
                    : detect_f32((const unsigned int*)srcs.p[0], threadIdx.x & 63);
    const unsigned int t  = blockIdx.x * 256u + threadIdx.x;
    const unsigned int ia = t * 8u;
    const unsigned int ib = ia + (CONV_TOTAL / 2);

    int tia, tib; size_t sa, sb;
    conv_locate(ia, tia, sa);
    conv_locate(ib, tib, sb);

    ushort8_t va, vb;
    if (isF32) {
        const float* pa = (const float*)srcs.p[tia] + sa;
        const float* pb = (const float*)srcs.p[tib] + sb;
        const float4 a0 = *reinterpret_cast<const float4*>(pa);
        const float4 a1 = *reinterpret_cast<const float4*>(pa + 4);
        const float4 b0 = *reinterpret_cast<const float4*>(pb);
        const float4 b1 = *reinterpret_cast<const float4*>(pb + 4);
        va = (ushort8_t){f2bf_bits(a0.x), f2bf_bits(a0.y), f2bf_bits(a0.z), f2bf_bits(a0.w),
                         f2bf_bits(a1.x), f2bf_bits(a1.y), f2bf_bits(a1.z), f2bf_bits(a1.w)};
        vb = (ushort8_t){f2bf_bits(b0.x), f2bf_bits(b0.y), f2bf_bits(b0.z), f2bf_bits(b0.w),
                         f2bf_bits(b1.x), f2bf_bits(b1.y), f2bf_bits(b1.z), f2bf_bits(b1.w)};
    } else {
        va = *reinterpret_cast<const ushort8_t*>((const unsigned short*)srcs.p[tia] + sa);
        vb = *reinterpret_cast<const ushort8_t*>((const unsigned short*)srcs.p[tib] + sb);
    }
    *reinterpret_cast<ushort8_t*>(dst + ia) = va;
    *reinterpret_cast<ushort8_t*>(dst + ib) = vb;
}

// ---------------------------------------------------------------------------
// Persistent fused GEMM+LSTM. 256 blocks, 2 tiles each (bm and bm+8, same bn).
// Per tile: 256 rows x 64 H-cols x 4 gates, BK=64, 512 thr = 8 waves (2Mx4N),
// 8-phase schedule. The 4 "ni" frag slots are the 4 gates.
// ---------------------------------------------------------------------------
#define GLL(SRC, DST) \
  __builtin_amdgcn_global_load_lds( \
      (const __attribute__((address_space(1))) void*)(SRC), \
      (__attribute__((address_space(3))) void*)(DST), 16, 0, 0)

#define STAGE_A(A0, A1, KOFF, BUF, KS) do { \
    GLL((A0) + (KOFF), lds + ((BUF) * 2 + (KS)) * 16384 + wvOff); \
    GLL((A1) + (KOFF), lds + ((BUF) * 2 + (KS)) * 16384 + 8192 + wvOff); \
  } while (0)

#define STAGE_B(B0, B1, KOFF, BUF, KS) do { \
    GLL((B0) + (KOFF), lds + 65536 + ((BUF) * 2 + (KS)) * 16384 + wvOff); \
    GLL((B1) + (KOFF), lds + 65536 + ((BUF) * 2 + (KS)) * 16384 + 8192 + wvOff); \
  } while (0)

// Phase: {ds_read frags | stage 1 half | barrier | lgkmcnt(0) | setprio(1)
//         16 MFMA | setprio(0) | [vmcnt(4)] | barrier}
#define PHASE(BUF, KS, MH, DOB, STAGE_STMT, DOVM) \
  { \
    const char* aSlot_ = lds + ((BUF) * 2 + (KS)) * 16384 + (MH) * 4096; \
    _Pragma("unroll") \
    for (int i_ = 0; i_ < 4; ++i_) \
      af[i_] = *reinterpret_cast<const bf16x8_t*>(aSlot_ + aoff[i_]); \
    if (DOB) { \
      const char* bSlot_ = lds + 65536 + ((BUF) * 2 + (KS)) * 16384; \
      _Pragma("unroll") \
      for (int i_ = 0; i_ < 4; ++i_) \
        bw[i_] = *reinterpret_cast<const bf16x8_t*>(bSlot_ + boff[i_]); \
    } \
    STAGE_STMT; \
    __builtin_amdgcn_s_barrier(); \
    asm volatile("s_waitcnt lgkmcnt(0)" ::: "memory"); \
    __builtin_amdgcn_s_setprio(1); \
    _Pragma("unroll") \
    for (int mi_ = 0; mi_ < 4; ++mi_) \
      _Pragma("unroll") \
      for (int ni_ = 0; ni_ < 4; ++ni_) \
        acc[(MH) * 4 + mi_][ni_] = __builtin_amdgcn_mfma_f32_16x16x32_bf16( \
            af[mi_], bw[ni_], acc[(MH) * 4 + mi_][ni_], 0, 0, 0); \
    __builtin_amdgcn_s_setprio(0); \
    if (DOVM) asm volatile("s_waitcnt vmcnt(4)" ::: "memory"); \
    __builtin_amdgcn_s_barrier(); \
  }

__global__ __launch_bounds__(512, 2) void gates_gemm_fast(
    const unsigned short* __restrict__ conv,
    const unsigned int* __restrict__ Xraw,
    const void* __restrict__ bi0, const void* __restrict__ bi1,
    const void* __restrict__ bi2, const void* __restrict__ bi3,
    const void* __restrict__ Cin,
    void* __restrict__ outp,                  // h [4096,2048], c follows
    int f32mode)
{
    __shared__ __align__(16) char lds[131072];   // A: 4x16K, B: 4x16K

    const int tid = threadIdx.x;
    // 256 blocks. XCD = orig%8 (round-robin). All 8 consumer blocks of W
    // panel bn land on XCD bn%8; each block does bm and bm+8 at the SAME bn
    // so round-2 W reads hit L2/L3.
    const int orig = blockIdx.x;              // 0..255
    const int xq   = orig & 7;
    const int j    = orig >> 3;               // 0..31
    const int bn   = xq + ((j & 3) << 3);     // H-column tile (64 cols), 0..31
    const int bm   = j >> 2;                  // M tile, 0..7; +8 = second tile

    const int isF32 = (f32mode >= 0) ? f32mode : detect_f32(Xraw, tid & 63);

    const char* Ab = (const char*)conv;
    const char* Wb = (const char*)(conv + CONV_W_ELS);

    const int o0   = tid << 4;
    const int l0   = o0 ^ (((o0 >> 7) & 3) << 4);
    const int srow = l0 >> 6;                 // 0..127
    const int skb  = l0 & 63;
    const char* pA0 = Ab + ((size_t)(bm * 256 + srow)) * 8192 + skb;
    const char* pA1 = pA0 + (size_t)128 * 8192;
    // B-tile row r: gate r>>6, W row (r>>6)*2048 + bn*64 + (r&63).
    const int br1 = srow + 128;
    const char* pB0 = Wb + ((size_t)((srow >> 6) * 2048 + bn * 64 + (srow & 63))) * 8192 + skb;
    const char* pB1 = Wb + ((size_t)((br1  >> 6) * 2048 + bn * 64 + (br1  & 63))) * 8192 + skb;

    const int waveU = __builtin_amdgcn_readfirstlane(tid >> 6);
    const int wvOff = waveU * 1024;
    const int lane = tid & 63;
    const int lr   = lane & 15;
    const int quad = lane >> 4;
    const int wid  = tid >> 6;
    const int wr   = wid >> 2;                // 0..1  (M half)
    const int wc   = wid & 3;                 // 0..3  (16-col quarter)

    int aoff[4], boff[4];
#pragma unroll
    for (int i = 0; i < 4; ++i) {
        int xa = (wr * 128 + i * 16 + lr) * 64 + quad * 16;
        aoff[i] = xa ^ (((xa >> 7) & 3) << 4);
        int xb = (i * 64 + wc * 16 + lr) * 64 + quad * 16;
        boff[i] = xb ^ (((xb >> 7) & 3) << 4);
    }

    // Bias (shared by both tiles: same bn). NO C register prefetch — spills
    // (R6: +47MB scratch writes). Epilogue loads C directly.
    const int colH = bn * 64 + wc * 16 + lr;
    float bvv[4];
    bvv[0] = isF32 ? ((const float*)bi0)[colH] : __bfloat162float(((const __hip_bfloat16*)bi0)[colH]);
    bvv[1] = isF32 ? ((const float*)bi1)[colH] : __bfloat162float(((const __hip_bfloat16*)bi1)[colH]);
    bvv[2] = isF32 ? ((const float*)bi2)[colH] : __bfloat162float(((const __hip_bfloat16*)bi2)[colH]);
    bvv[3] = isF32 ? ((const float*)bi3)[colH] : __bfloat162float(((const __hip_bfloat16*)bi3)[colH]);

    floatx4_t acc[8][4];
#pragma unroll
    for (int a = 0; a < 8; ++a)
#pragma unroll
        for (int g = 0; g < 4; ++g)
            acc[a][g] = (floatx4_t){0.f, 0.f, 0.f, 0.f};

    // Prologue: tile0 (k0,k1) + tile1 (k0); vmcnt(4) => bias + t0 landed
    // (youngest 4 = t1k0's stages).
    STAGE_A(pA0, pA1, 0, 0, 0);   STAGE_B(pB0, pB1, 0, 0, 0);
    STAGE_A(pA0, pA1, 64, 0, 1);  STAGE_B(pB0, pB1, 64, 0, 1);
    STAGE_A(pA0, pA1, 128, 1, 0); STAGE_B(pB0, pB1, 128, 1, 0);
    asm volatile("s_waitcnt vmcnt(4)" ::: "memory");
    __builtin_amdgcn_s_barrier();

    auto epilogue = [&](int bmE) {
#pragma unroll
        for (int a8 = 0; a8 < 8; ++a8) {
            const int rowBase = bmE * 256 + wr * 128 + (a8 >> 2) * 64 + (a8 & 3) * 16 + quad * 4;
#pragma unroll
            for (int r = 0; r < 4; ++r) {
                const size_t idx = (size_t)(rowBase + r) * K_DIM + colH;
                const float cv = isF32 ? ((const float*)Cin)[idx]
                                       : bf_bits2f(((const unsigned short*)Cin)[idx]);
                const float gi = acc[a8][0][r] + bvv[0];
                const float go = acc[a8][1][r] + bvv[1];
                const float gf = acc[a8][2][r] + bvv[2];
                const float gc = acc[a8][3][r] + bvv[3];
                const float it = sigmoid_f(gi);
                const float ot = sigmoid_f(go);
                const float ft = sigmoid_f(gf);
                const float ct = tanh_f(gc);
                const float nc = ft * cv + it * ct;
                const float nh = ot * tanh_f(nc);
                if (isF32) {
                    ((float*)outp)[idx] = nh;
                    ((float*)outp)[(size_t)BHT + idx] = nc;
                } else {
                    ((unsigned short*)outp)[idx] = f2bf_bits(nh);
                    ((unsigned short*)outp)[(size_t)BHT + idx] = f2bf_bits(nc);
                }
            }
        }
    };

    // Steady state per iter (t=2i in buf0, t+1 in buf1):
    //  P1 rd buf0k0, st A(t+1,k1)->b1k1   P5 rd buf1k0, st A(t+2,k1)->b0k1
    //  P2 rd buf0k0, st B(t+1,k1)         P6 rd buf1k0, st B(t+2,k1)
    //  P3 rd buf0k1, st A(t+2,k0)->b0k0   P7 rd buf1k1, st A(t+3,k0)->b1k0
    //  P4 rd buf0k1, st B(t+2,k0); vm4    P8 rd buf1k1, st B(t+3,k0); vm4
    // W-A-R: every stage targets a slot last read >=1 barrier earlier.
    // R-A-W: vm4@P4 covers P5/P7; vm4@P8 covers next-iter P1/P3.
    // TILE-1 FINAL ITER: P3..P8's stages (base-shifted) ARE tile-2's prologue
    // into {b0k0,b0k1,b1k0}. At final P8's vm4+barrier, b0k0/b0k1 are landed
    // globally; only b1k0's 4 ops may fly, drained by tile-2's P4 vm4 before
    // P5 reads b1k0 -> NO inter-tile drain/barrier (HW-validated R5/R6).
    // Waves flow from P8 into epilogue-1 while t2 staging is in flight.
    bf16x8_t af[4], bw[4];
#pragma unroll 1
    for (int it2 = 0; it2 < NTILE / 2; ++it2) {
        const int kt = it2 * 256;
        const bool lastI = (it2 == NTILE / 2 - 1);
        const char* nA0 = lastI ? (pA0 + (ASHIFT - 8192)) : pA0;
        const char* nA1 = lastI ? (pA1 + (ASHIFT - 8192)) : pA1;
        const char* nB0 = lastI ? (pB0 - 8192) : pB0;
        const char* nB1 = lastI ? (pB1 - 8192) : pB1;
        PHASE(0, 0, 0, 1, STAGE_A(pA0, pA1, kt + 192, 1, 1), 0)
        PHASE(0, 0, 1, 0, STAGE_B(pB0, pB1, kt + 192, 1, 1), 0)
        PHASE(0, 1, 0, 1, STAGE_A(nA0, nA1, kt + 256, 0, 0), 0)
        PHASE(0, 1, 1, 0, STAGE_B(nB0, nB1, kt + 256, 0, 0), 1)
        PHASE(1, 0, 0, 1, STAGE_A(nA0, nA1, kt + 320, 0, 1), 0)
        PHASE(1, 0, 1, 0, STAGE_B(nB0, nB1, kt + 320, 0, 1), 0)
        PHASE(1, 1, 0, 1, STAGE_A(nA0, nA1, kt + 384, 1, 0), 0)
        PHASE(1, 1, 1, 0, STAGE_B(nB0, nB1, kt + 384, 1, 0), 1)
    }

    // Epilogue-1 (C loaded directly) overlaps tile-2's in-flight prologue
    // stages; acc re-zero; straight into tile-2.
    epilogue(bm);
#pragma unroll
    for (int a = 0; a < 8; ++a)
#pragma unroll
        for (int g = 0; g < 4; ++g)
            acc[a][g] = (floatx4_t){0.f, 0.f, 0.f, 0.f};

    // Tile-2 K-loop (A bases +ASHIFT; B panel identical -> L2-hot). Final-iter
    // stages read harmless in-bounds garbage (<=8.5KB past W end; 64KB pad).
    const char* qA0 = pA0 + ASHIFT;
    const char* qA1 = pA1 + ASHIFT;
#pragma unroll 1
    for (int it2 = 0; it2 < NTILE / 2; ++it2) {
        const int kt = it2 * 256;
        PHASE(0, 0, 0, 1, STAGE_A(qA0, qA1, kt + 192, 1, 1), 0)
        PHASE(0, 0, 1, 0, STAGE_B(pB0, pB1, kt + 192, 1, 1), 0)
        PHASE(0, 1, 0, 1, STAGE_A(qA0, qA1, kt + 256, 0, 0), 0)
        PHASE(0, 1, 1, 0, STAGE_B(pB0, pB1, kt + 256, 0, 0), 1)
        PHASE(1, 0, 0, 1, STAGE_A(qA0, qA1, kt + 320, 0, 1), 0)
        PHASE(1, 0, 1, 0, STAGE_B(pB0, pB1, kt + 320, 0, 1), 0)
        PHASE(1, 1, 0, 1, STAGE_A(qA0, qA1, kt + 384, 1, 0), 0)
        PHASE(1, 1, 1, 0, STAGE_B(pB0, pB1, kt + 384, 1, 0), 1)
    }
    asm volatile("s_waitcnt vmcnt(0)" ::: "memory");  // drain garbage stages
    epilogue(bm + 8);
}

// ---------------------------------------------------------------------------
// Slow fallback GEMM (verified earlier): ds_write staging + in-kernel convert.
// ---------------------------------------------------------------------------
__global__ __launch_bounds__(256) void gates_gemm_slow(
    const void* __restrict__ X, const void* __restrict__ Hm,
    const void* __restrict__ Wx0, const void* __restrict__ Wx1,
    const void* __restrict__ Wx2, const void* __restrict__ Wx3,
    const void* __restrict__ Wh0, const void* __restrict__ Wh1,
    const void* __restrict__ Wh2, const void* __restrict__ Wh3,
    const void* __restrict__ bi0, const void* __restrict__ bi1,
    const void* __restrict__ bi2, const void* __restrict__ bi3,
    const int* __restrict__ flagp, int m0,
    __hip_bfloat16* __restrict__ gates)
{
    __shared__ __align__(16) char lds[16384];
    const int isF32 = *flagp;
    const int esz   = isF32 ? 4 : 2;

    const int tid     = threadIdx.x;
    const int bm      = blockIdx.y;
    const int bn      = blockIdx.x;
    const int gate    = bn >> 4;
    const int nInGate = (bn & 15) << 7;

    const void* Wx = (gate == 0) ? Wx0 : (gate == 1) ? Wx1 : (gate == 2) ? Wx2 : Wx3;
    const void* Wh = (gate == 0) ? Wh0 : (gate == 1) ? Wh1 : (gate == 2) ? Wh2 : Wh3;
    const void* bs = (gate == 0) ? bi0 : (gate == 1) ? bi1 : (gate == 2) ? bi2 : bi3;

    const int ldRow = tid >> 2;
    const int sub   = tid & 3;
    const size_t rowStride = (size_t)K_DIM * esz;
    const size_t rowHalf   = 64 * rowStride;
    const char* aG  = (const char*)X  + (size_t)(m0 + bm * 128 + ldRow) * rowStride + (size_t)sub * 8 * esz;
    const char* hG  = (const char*)Hm + (size_t)(m0 + bm * 128 + ldRow) * rowStride + (size_t)sub * 8 * esz;
    const char* wxG = (const char*)Wx + (size_t)(nInGate + ldRow) * rowStride + (size_t)sub * 8 * esz;
    const char* whG = (const char*)Wh + (size_t)(nInGate + ldRow) * rowStride + (size_t)sub * 8 * esz;

    char* const dA0 = lds + tid * 16;
    char* const dA1 = lds + 4096 + tid * 16;
    char* const dB0 = lds + 8192 + tid * 16;
    char* const dB1 = lds + 12288 + tid * 16;
    const char* const AsB = lds;
    const char* const BsB = lds + 8192;

    const int lane = tid & 63;
    const int wave = tid >> 6;
    const int wm   = (wave & 1) << 6;
    const int wn   = (wave >> 1) << 6;
    const int lr   = lane & 15;
    const int quad = lane >> 4;

    int aOff[4], bOff[4];
#pragma unroll
    for (int i = 0; i < 4; ++i) {
        aOff[i] = ((wm + i * 16 + lr) * 32 + quad * 8) * 2;
        bOff[i] = ((wn + i * 16 + lr) * 32 + quad * 8) * 2;
    }

    floatx4_t acc[4][4];
#pragma unroll
    for (int mi = 0; mi < 4; ++mi)
#pragma unroll
        for (int ni = 0; ni < 4; ++ni)
            acc[mi][ni] = (floatx4_t){0.f, 0.f, 0.f, 0.f};

#pragma unroll 1
    for (int seg = 0; seg < 2; ++seg) {
        const char* ag = seg ? hG : aG;
        const char* bg = seg ? whG : wxG;
#pragma unroll 1
        for (int ke = 0; ke < K_DIM; ke += 32) {
            const size_t kb = (size_t)ke * esz;
            ushort8_t va0, va1, vb0, vb1;
            if (!isF32) {
                va0 = *reinterpret_cast<const ushort8_t*>(ag + kb);
                va1 = *reinterpret_cast<const ushort8_t*>(ag + rowHalf + kb);
                vb0 = *reinterpret_cast<const ushort8_t*>(bg + kb);
                vb1 = *reinterpret_cast<const ushort8_t*>(bg + rowHalf + kb);
            } else {
                const char* p; float4 f0, f1;
                p = ag + kb;           f0 = *reinterpret_cast<const float4*>(p);
                f1 = *reinterpret_cast<const float4*>(p + 16);
                va0 = (ushort8_t){f2bf_bits(f0.x), f2bf_bits(f0.y), f2bf_bits(f0.z), f2bf_bits(f0.w),
                                  f2bf_bits(f1.x), f2bf_bits(f1.y), f2bf_bits(f1.z), f2bf_bits(f1.w)};
                p = ag + rowHalf + kb; f0 = *reinterpret_cast<const float4*>(p);
                f1 = *reinterpret_cast<const float4*>(p + 16);
                va1 = (ushort8_t){f2bf_bits(f0.x), f2bf_bits(f0.y), f2bf_bits(f0.z), f2bf_bits(f0.w),
                                  f2bf_bits(f1.x), f2bf_bits(f1.y), f2bf_bits(f1.z), f2bf_bits(f1.w)};
                p = bg + kb;           f0 = *reinterpret_cast<const float4*>(p);
                f1 = *reinterpret_cast<const float4*>(p + 16);
                vb0 = (ushort8_t){f2bf_bits(f0.x), f2bf_bits(f0.y), f2bf_bits(f0.z), f2bf_bits(f0.w),
                                  f2bf_bits(f1.x), f2bf_bits(f1.y), f2bf_bits(f1.z), f2bf_bits(f1.w)};
                p = bg + rowHalf + kb; f0 = *reinterpret_cast<const float4*>(p);
                f1 = *reinterpret_cast<const float4*>(p + 16);
                vb1 = (ushort8_t){f2bf_bits(f0.x), f2bf_bits(f0.y), f2bf_bits(f0.z), f2bf_bits(f0.w),
                                  f2bf_bits(f1.x), f2bf_bits(f1.y), f2bf_bits(f1.z), f2bf_bits(f1.w)};
            }
            __syncthreads();
            *reinterpret_cast<ushort8_t*>(dA0) = va0;
            *reinterpret_cast<ushort8_t*>(dA1) = va1;
            *reinterpret_cast<ushort8_t*>(dB0) = vb0;
            *reinterpret_cast<ushort8_t*>(dB1) = vb1;
            __syncthreads();

            bf16x8_t af[4], bwv[4];
#pragma unroll
            for (int i = 0; i < 4; ++i) af[i] = *reinterpret_cast<const bf16x8_t*>(AsB + aOff[i]);
#pragma unroll
            for (int i = 0; i < 4; ++i) bwv[i] = *reinterpret_cast<const bf16x8_t*>(BsB + bOff[i]);
#pragma unroll
            for (int mi = 0; mi < 4; ++mi)
#pragma unroll
                for (int ni = 0; ni < 4; ++ni)
                    acc[mi][ni] = __builtin_amdgcn_mfma_f32_16x16x32_bf16(
                        af[mi], bwv[ni], acc[mi][ni], 0, 0, 0);
        }
    }

    float bv[4];
#pragma unroll
    for (int ni = 0; ni < 4; ++ni) {
        const int col = nInGate + wn + ni * 16 + lr;
        bv[ni] = isF32 ? ((const float*)bs)[col]
                       : __bfloat162float(((const __hip_bfloat16*)bs)[col]);
    }
#pragma unroll
    for (int mi = 0; mi < 4; ++mi) {
        const int rowBase = bm * 128 + wm + mi * 16 + quad * 4;
#pragma unroll
        for (int ni = 0; ni < 4; ++ni) {
            const size_t colBase = (size_t)gate * 2048 + nInGate + wn + ni * 16 + lr;
#pragma unroll
            for (int r = 0; r < 4; ++r)
                gates[(size_t)(rowBase + r) * NG + colBase] =
                    __float2bfloat16(acc[mi][ni][r] + bv[ni]);
        }
    }
}

// ---------------------------------------------------------------------------
// Pointwise LSTM combine (fallback path only).
// ---------------------------------------------------------------------------
__global__ __launch_bounds__(256) void lstm_pointwise_kernel(
    const unsigned short* __restrict__ gates,
    const void* __restrict__ Cin,
    void* __restrict__ out,
    const int* __restrict__ flagp, int m0)
{
    const int isF32 = *flagp;
    const int lidx = (blockIdx.x * 256 + threadIdx.x) * 4;
    const int b = lidx >> 11;
    const int j = lidx & 2047;
    const unsigned short* g = gates + (size_t)b * NG + j;
    const size_t gidx = (size_t)m0 * 2048 + (size_t)lidx;

    const ushort4 ui = *reinterpret_cast<const ushort4*>(g);
    const ushort4 uo = *reinterpret_cast<const ushort4*>(g + 2048);
    const ushort4 uf = *reinterpret_cast<const ushort4*>(g + 4096);
    const ushort4 uc = *reinterpret_cast<const ushort4*>(g + 6144);
    const float gi[4] = {bf_bits2f(ui.x), bf_bits2f(ui.y), bf_bits2f(ui.z), bf_bits2f(ui.w)};
    const float go[4] = {bf_bits2f(uo.x), bf_bits2f(uo.y), bf_bits2f(uo.z), bf_bits2f(uo.w)};
    const float gf[4] = {bf_bits2f(uf.x), bf_bits2f(uf.y), bf_bits2f(uf.z), bf_bits2f(uf.w)};
    const float gc[4] = {bf_bits2f(uc.x), bf_bits2f(uc.y), bf_bits2f(uc.z), bf_bits2f(uc.w)};

    float cv[4];
    if (isF32) {
        const float4 c4 = *reinterpret_cast<const float4*>((const float*)Cin + gidx);
        cv[0] = c4.x; cv[1] = c4.y; cv[2] = c4.z; cv[3] = c4.w;
    } else {
        const ushort4 u = *reinterpret_cast<const ushort4*>((const unsigned short*)Cin + gidx);
        cv[0] = bf_bits2f(u.x); cv[1] = bf_bits2f(u.y);
        cv[2] = bf_bits2f(u.z); cv[3] = bf_bits2f(u.w);
    }

    float nh[4], nc[4];
#pragma unroll
    for (int k = 0; k < 4; ++k) {
        const float it = sigmoid_f(gi[k]);
        const float ot = sigmoid_f(go[k]);
        const float ft = sigmoid_f(gf[k]);
        const float ct = tanh_f(gc[k]);
        nc[k] = ft * cv[k] + it * ct;
        nh[k] = ot * tanh_f(nc[k]);
    }

    if (isF32) {
        float* oH = (float*)out;
        float* oC = oH + (size_t)BHT;
        *reinterpret_cast<float4*>(oH + gidx) = make_float4(nh[0], nh[1], nh[2], nh[3]);
        *reinterpret_cast<float4*>(oC + gidx) = make_float4(nc[0], nc[1], nc[2], nc[3]);
    } else {
        unsigned short* oH = (unsigned short*)out;
        unsigned short* oC = oH + (size_t)BHT;
        *reinterpret_cast<ushort4*>(oH + gidx) =
            make_ushort4(f2bf_bits(nh[0]), f2bf_bits(nh[1]), f2bf_bits(nh[2]), f2bf_bits(nh[3]));
        *reinterpret_cast<ushort4*>(oC + gidx) =
            make_ushort4(f2bf_bits(nc[0]), f2bf_bits(nc[1]), f2bf_bits(nc[2]), f2bf_bits(nc[3]));
    }
}

extern "C" void kernel_launch(void* const* d_in, const int* in_sizes, int n_in,
                              void* d_out, int out_size, void* d_ws, size_t ws_size,
                              hipStream_t stream) {
    (void)out_size;
    const void* X   = d_in[0];
    const void* Hm  = d_in[1];
    const void* C   = d_in[2];
    const void* Wxi = d_in[3];
    const void* Wxo = d_in[4];
    const void* Wxf = d_in[5];
    const void* Wxc = d_in[6];
    const void* bi  = d_in[7];
    const void* bo  = d_in[8];
    const void* bfp = d_in[9];
    const void* bc  = d_in[10];
    const void* Whi = d_in[11];
    const void* Who = d_in[12];
    const void* Whf = d_in[13];
    const void* Whc = d_in[14];

    // Host-side dtype resolution from X's byte size; -1 = ambiguous -> device
    // detect fallback (covers in_sizes being element counts).
    int f32mode = -1;
    if (in_sizes && n_in > 0) {
        const long long bytesF32  = (long long)B_DIM * K_DIM * 4;  // 33554432
        const long long bytesBF16 = (long long)B_DIM * K_DIM * 2;  // 16777216
        if ((long long)in_sizes[0] == bytesF32)       f32mode = 1;
        else if ((long long)in_sizes[0] == bytesBF16) f32mode = 0;
    }

    const dim3 blk(256);

    if (ws_size >= FAST_NEED) {
        unsigned short* conv = (unsigned short*)d_ws;

        SrcPtrs sp;
        sp.p[0] = X;  sp.p[1] = Hm;
        sp.p[2] = Wxi; sp.p[3] = Wxo; sp.p[4] = Wxf; sp.p[5] = Wxc;
        sp.p[6] = Whi; sp.p[7] = Who; sp.p[8] = Whf; sp.p[9] = Whc;

        // 12288 blocks x 256 thr x 2 chunks = 48M els.
        convert_kernel<<<dim3(12288), blk, 0, stream>>>(sp, conv, f32mode);

        gates_gemm_fast<<<dim3(256), dim3(512), 0, stream>>>(
            conv, (const unsigned int*)X, bi, bo, bfp, bc, C, d_out, f32mode);
    } else {
        const size_t flagOff = (ws_size - 4) & ~(size_t)15;
        int* flag = (int*)((char*)d_ws + flagOff);
        dtype_probe_kernel<<<1, 64, 0, stream>>>((const unsigned int*)X, flag);

        __hip_bfloat16* gates = (__hip_bfloat16*)d_ws;
        int rows = B_DIM;
        while ((size_t)rows * NG * 2 > flagOff && rows > 128) rows >>= 1;
        for (int m0 = 0; m0 < B_DIM; m0 += rows) {
            gates_gemm_slow<<<dim3(64, rows / 128), blk, 0, stream>>>(
                X, Hm, Wxi, Wxo, Wxf, Wxc, Whi, Who, Whf, Whc,
                bi, bo, bfp, bc, flag, m0, gates);
            lstm_pointwise_kernel<<<dim3(rows * 2048 / 1024), blk, 0, stream>>>(
                (const unsigned short*)gates, C, d_out, flag, m0);
        }
    }
}